// Round 1
// baseline (1536.923 us; speedup 1.0000x reference)
//
#include <hip/hip_runtime.h>
#include <math.h>

// Problem constants
// x: (16,64,3,32,32) x2 concat -> (1024,6,32,32)
// conv1 6->64 k3 p1 -> BN -> ReLU -> pool2 -> (1024,64,16,16)
// conv2 64->64 k3 p1 -> BN -> ReLU -> pool2 -> (1024,64,8,8) = feats (1024,4096)
// RNN T=64 steps over feats rows n=b*64+t ; head -> sigmoid (16,1)

// ---------------------------------------------------------------------------
// conv1: template STATS pass (per-channel sum/sumsq partials) / APPLY pass
// grid (1024, 4), block 256.  LDS: padded input image + 16-channel weight tile.
// NOTE: conv bias cancels in BN (variance shift-invariant) -> never applied.
// ---------------------------------------------------------------------------
template<bool STATS>
__global__ __launch_bounds__(256)
void conv1_kernel(const float* __restrict__ x1, const float* __restrict__ x2,
                  const float* __restrict__ w1, const float* __restrict__ bn,
                  float* __restrict__ out)
{
  __shared__ float xin[6*34*34];   // padded 6x34x34
  __shared__ float wt[16*54];
  __shared__ float wred[4*16*2];
  const int n = blockIdx.x, ct = blockIdx.y, tid = threadIdx.x;

  for (int idx = tid; idx < 6*34*34; idx += 256) {
    int ci = idx / 1156, rem = idx - ci*1156;
    int r = rem / 34, c = rem - r*34;
    float v = 0.f;
    if (r >= 1 && r <= 32 && c >= 1 && c <= 32) {
      int p = (r-1)*32 + (c-1);
      v = (ci < 3) ? x1[n*3072 + ci*1024 + p] : x2[n*3072 + (ci-3)*1024 + p];
    }
    xin[idx] = v;
  }
  for (int idx = tid; idx < 16*54; idx += 256) wt[idx] = w1[ct*864 + idx];
  __syncthreads();

  const int ph = tid >> 4, pw = tid & 15;   // pooled coords (16x16)
  float acc[16][4];
  #pragma unroll
  for (int co = 0; co < 16; ++co) { acc[co][0]=0.f; acc[co][1]=0.f; acc[co][2]=0.f; acc[co][3]=0.f; }

  #pragma unroll
  for (int ci = 0; ci < 6; ++ci) {
    const float* base = &xin[ci*1156 + (2*ph)*34 + 2*pw];
    float r[4][4];
    #pragma unroll
    for (int i = 0; i < 4; ++i)
      #pragma unroll
      for (int j = 0; j < 4; ++j)
        r[i][j] = base[i*34 + j];
    #pragma unroll
    for (int co = 0; co < 16; ++co) {
      #pragma unroll
      for (int kh = 0; kh < 3; ++kh) {
        #pragma unroll
        for (int kw = 0; kw < 3; ++kw) {
          float wv = wt[co*54 + ci*9 + kh*3 + kw];
          acc[co][0] = fmaf(r[kh  ][kw  ], wv, acc[co][0]);
          acc[co][1] = fmaf(r[kh  ][kw+1], wv, acc[co][1]);
          acc[co][2] = fmaf(r[kh+1][kw  ], wv, acc[co][2]);
          acc[co][3] = fmaf(r[kh+1][kw+1], wv, acc[co][3]);
        }
      }
    }
  }

  if (STATS) {
    const int lane = tid & 63, wv = tid >> 6;
    #pragma unroll
    for (int co = 0; co < 16; ++co) {
      float s  = acc[co][0]+acc[co][1]+acc[co][2]+acc[co][3];
      float ss = acc[co][0]*acc[co][0]+acc[co][1]*acc[co][1]
               + acc[co][2]*acc[co][2]+acc[co][3]*acc[co][3];
      #pragma unroll
      for (int d = 32; d; d >>= 1) { s += __shfl_xor(s, d); ss += __shfl_xor(ss, d); }
      if (lane == 0) { wred[(wv*16+co)*2] = s; wred[(wv*16+co)*2+1] = ss; }
    }
    __syncthreads();
    if (tid < 16) {
      float s = 0.f, ss = 0.f;
      #pragma unroll
      for (int w = 0; w < 4; ++w) { s += wred[(w*16+tid)*2]; ss += wred[(w*16+tid)*2+1]; }
      int c = ct*16 + tid;
      out[c*2048 + n*2]     = s;   // layout [c][n][2] for coalesced finalize
      out[c*2048 + n*2 + 1] = ss;
    }
  } else {
    #pragma unroll
    for (int co = 0; co < 16; ++co) {
      int c = ct*16 + co;
      float sc = bn[c], sh = bn[64+c];
      float y0 = fmaxf(fmaf(acc[co][0], sc, sh), 0.f);
      float y1 = fmaxf(fmaf(acc[co][1], sc, sh), 0.f);
      float y2 = fmaxf(fmaf(acc[co][2], sc, sh), 0.f);
      float y3 = fmaxf(fmaf(acc[co][3], sc, sh), 0.f);
      out[((n*64 + c)*16 + ph)*16 + pw] = fmaxf(fmaxf(y0,y1), fmaxf(y2,y3));
    }
  }
}

// ---------------------------------------------------------------------------
// BN finalize: per-channel mean/var -> scale/shift.  grid 64, block 256.
// ---------------------------------------------------------------------------
__global__ __launch_bounds__(256)
void bn_finalize(const float* __restrict__ part, const float* __restrict__ g,
                 const float* __restrict__ beta, float inv_cnt, float* __restrict__ bn)
{
  __shared__ float red[8];
  const int c = blockIdx.x, tid = threadIdx.x;
  float s = 0.f, ss = 0.f;
  for (int n = tid; n < 1024; n += 256) {
    s  += part[c*2048 + n*2];
    ss += part[c*2048 + n*2 + 1];
  }
  #pragma unroll
  for (int d = 32; d; d >>= 1) { s += __shfl_xor(s, d); ss += __shfl_xor(ss, d); }
  if ((tid & 63) == 0) { red[(tid>>6)*2] = s; red[(tid>>6)*2+1] = ss; }
  __syncthreads();
  if (tid == 0) {
    float S  = red[0]+red[2]+red[4]+red[6];
    float SS = red[1]+red[3]+red[5]+red[7];
    float m  = S * inv_cnt;
    float var = SS * inv_cnt - m*m;
    float sc = g[c] * rsqrtf(var + 1e-5f);
    bn[c]    = sc;
    bn[64+c] = beta[c] - m*sc;
  }
}

// ---------------------------------------------------------------------------
// conv2 single pass: raw conv -> per-channel partial stats + pooled max AND min
// (pool commutes with channel affine; min kept so negative gamma stays correct)
// grid 1024, block 256 (cg=tid>>4 co-group of 4, pg=tid&15 pixel row).
// ---------------------------------------------------------------------------
__global__ __launch_bounds__(256)
void conv2_kernel(const float* __restrict__ pool1, const float* __restrict__ w2,
                  float* __restrict__ part, float* __restrict__ pmax, float* __restrict__ pmin)
{
  __shared__ float xin[8*18*18];   // 8-ci chunk, padded 18x18
  __shared__ float wt[64*8*9];
  const int n = blockIdx.x, tid = threadIdx.x;
  const int cg = tid >> 4, pg = tid & 15;
  float acc[4][16];
  #pragma unroll
  for (int a = 0; a < 4; ++a)
    #pragma unroll
    for (int b = 0; b < 16; ++b) acc[a][b] = 0.f;

  for (int ch = 0; ch < 8; ++ch) {
    const int ci0 = ch*8;
    for (int idx = tid; idx < 8*18*18; idx += 256) {
      int ci = idx / 324, rem = idx - ci*324;
      int r = rem / 18, c = rem - r*18;
      float v = 0.f;
      if (r >= 1 && r <= 16 && c >= 1 && c <= 16)
        v = pool1[(n*64 + ci0+ci)*256 + (r-1)*16 + (c-1)];
      xin[idx] = v;
    }
    for (int idx = tid; idx < 64*72; idx += 256) {
      int co = idx / 72, rem = idx - co*72;
      wt[idx] = w2[co*576 + ci0*9 + rem];
    }
    __syncthreads();
    #pragma unroll
    for (int ci = 0; ci < 8; ++ci) {
      #pragma unroll
      for (int kh = 0; kh < 3; ++kh) {
        const float* base = &xin[ci*324 + (pg+kh)*18];
        float r[18];
        #pragma unroll
        for (int j = 0; j < 18; ++j) r[j] = base[j];
        #pragma unroll
        for (int co = 0; co < 4; ++co) {
          const int wb = (cg*4+co)*72 + ci*9 + kh*3;
          float w0 = wt[wb], w1 = wt[wb+1], w2v = wt[wb+2];
          #pragma unroll
          for (int p = 0; p < 16; ++p)
            acc[co][p] = fmaf(r[p], w0, fmaf(r[p+1], w1, fmaf(r[p+2], w2v, acc[co][p])));
        }
      }
    }
    __syncthreads();
  }

  #pragma unroll
  for (int co = 0; co < 4; ++co) {
    const int c = cg*4 + co;
    float s = 0.f, ss = 0.f;
    #pragma unroll
    for (int p = 0; p < 16; ++p) { s += acc[co][p]; ss = fmaf(acc[co][p], acc[co][p], ss); }
    #pragma unroll
    for (int d = 1; d < 16; d <<= 1) { s += __shfl_xor(s, d); ss += __shfl_xor(ss, d); }
    if (pg == 0) { part[c*2048 + n*2] = s; part[c*2048 + n*2 + 1] = ss; }

    float hx[8], hn[8];
    #pragma unroll
    for (int w = 0; w < 8; ++w) {
      hx[w] = fmaxf(acc[co][2*w], acc[co][2*w+1]);
      hn[w] = fminf(acc[co][2*w], acc[co][2*w+1]);
    }
    #pragma unroll
    for (int w = 0; w < 8; ++w) {
      float ox = fmaxf(hx[w], __shfl_xor(hx[w], 1));   // rows pg, pg^1
      float on = fminf(hn[w], __shfl_xor(hn[w], 1));
      if (!(pg & 1)) {
        int off = ((n*64 + c) << 6) + (pg >> 1)*8 + w;   // feats layout n*4096+c*64+p
        pmax[off] = ox;
        pmin[off] = on;
      }
    }
  }
}

// feats = relu(affine(pooled raw)) -- elementwise.  grid 16384, block 256.
__global__ __launch_bounds__(256)
void conv2_apply(const float* __restrict__ pmax, const float* __restrict__ pmin,
                 const float* __restrict__ bn, float* __restrict__ feats)
{
  int idx = blockIdx.x*256 + threadIdx.x;   // 1024*4096 exact
  int c = (idx >> 6) & 63;
  float sc = bn[c], sh = bn[64+c];
  float v = (sc >= 0.f) ? pmax[idx] : pmin[idx];
  feats[idx] = fmaxf(fmaf(v, sc, sh), 0.f);
}

// ---------------------------------------------------------------------------
// preQ = feats @ Q_w[:, :4096]^T  (M=1024, K=4096, N=100), K split 4 ways.
// grid (64 rowblocks, 4 ksplit), block 256 (r=tid>>4 row, cg=tid&15).
// LDS padded stride 65 for bank-conflict-free reads; cols j = cg + 16*c.
// ---------------------------------------------------------------------------
__global__ __launch_bounds__(256)
void preq_part(const float* __restrict__ feats, const float* __restrict__ Qw,
               float* __restrict__ part)
{
  __shared__ float fL[16*65];
  __shared__ float qL[128*65];
  const int rb = blockIdx.x, ks = blockIdx.y, tid = threadIdx.x;
  const int r = tid >> 4, cg = tid & 15;
  const int n0 = rb*16, k0 = ks*1024;
  float acc[8];
  #pragma unroll
  for (int c = 0; c < 8; ++c) acc[c] = 0.f;

  for (int kk = 0; kk < 16; ++kk) {
    {
      int i = tid*4;
      int rr = i >> 6, cc = i & 63;
      float4 v = *(const float4*)&feats[(n0+rr)*4096 + k0 + kk*64 + cc];
      fL[rr*65+cc] = v.x; fL[rr*65+cc+1] = v.y; fL[rr*65+cc+2] = v.z; fL[rr*65+cc+3] = v.w;
    }
    #pragma unroll
    for (int t2 = 0; t2 < 8; ++t2) {
      int i = (tid + t2*256)*4;          // 0..8191
      int row = i >> 6, col = i & 63;
      float4 v = make_float4(0.f,0.f,0.f,0.f);
      if (row < 100) v = *(const float4*)&Qw[row*4196 + k0 + kk*64 + col];
      qL[row*65+col] = v.x; qL[row*65+col+1] = v.y; qL[row*65+col+2] = v.z; qL[row*65+col+3] = v.w;
    }
    __syncthreads();
    #pragma unroll 8
    for (int k = 0; k < 64; ++k) {
      float f = fL[r*65 + k];
      #pragma unroll
      for (int c = 0; c < 8; ++c)
        acc[c] = fmaf(f, qL[(cg + 16*c)*65 + k], acc[c]);
    }
    __syncthreads();
  }
  #pragma unroll
  for (int c = 0; c < 8; ++c) {
    int j = cg + 16*c;
    if (j < 100) part[(ks*1024 + n0 + r)*100 + j] = acc[c];
  }
}

__global__ __launch_bounds__(256)
void preq_reduce(const float* __restrict__ part, const float* __restrict__ Qb,
                 float* __restrict__ preQ)
{
  int idx = blockIdx.x*256 + threadIdx.x;  // 102400 exact
  if (idx < 1024*100) {
    int j = idx - (idx/100)*100;
    float s = part[idx] + part[102400 + idx] + part[2*102400 + idx] + part[3*102400 + idx];
    preQ[idx] = s + Qb[j];
  }
}

// ---------------------------------------------------------------------------
// RNN (64 sequential steps) + head. grid 16 (one block per batch b), block 512.
// Threads tid<400: o=tid>>2 output, q4=tid&3 k-quarter; R_w row quarter (100f)
// and Q_w recurrent quarter (25f) held in registers. Ha in LDS.
// ---------------------------------------------------------------------------
__global__ __launch_bounds__(512, 2)
void rnn_head(const float* __restrict__ preQ, const float* __restrict__ Rw,
              const float* __restrict__ Rb, const float* __restrict__ Qw,
              const float* __restrict__ Ow, const float* __restrict__ Ob,
              const float* __restrict__ f1w, const float* __restrict__ f1b,
              const float* __restrict__ f2w, const float* __restrict__ f2b,
              float* __restrict__ out)
{
  __shared__ __align__(16) float ha[400];
  __shared__ float rt[100];
  __shared__ float qt[100];
  __shared__ float pq[6400];
  __shared__ float rb[100];
  __shared__ __align__(16) float ol[128];
  __shared__ float f1[64];
  const int b = blockIdx.x, tid = threadIdx.x;

  for (int i = tid; i < 6400; i += 512) pq[i] = preQ[b*6400 + i];
  if (tid < 100) rb[tid] = Rb[tid];
  if (tid < 400) ha[tid] = 0.f;

  const int o = tid >> 2, q4 = tid & 3;
  float rw[100], qw[25];
  if (tid < 400) {
    const float* rsrc = &Rw[o*400 + q4*100];
    #pragma unroll
    for (int i = 0; i < 25; ++i) {
      float4 v = *(const float4*)&rsrc[i*4];
      rw[i*4] = v.x; rw[i*4+1] = v.y; rw[i*4+2] = v.z; rw[i*4+3] = v.w;
    }
    const float* qsrc = &Qw[o*4196 + 4096 + q4*25];
    #pragma unroll
    for (int i = 0; i < 25; ++i) qw[i] = qsrc[i];
  }
  const int ja = (tid < 400) ? (tid / 100) : 0;
  const int jq = tid - ja*100;
  const float Aa = (ja==0) ? 0.f : (ja==1) ? 0.25f : (ja==2) ? 0.5f : 0.95f;
  const float Ba = 1.f - Aa;
  __syncthreads();

  for (int t = 0; t < 64; ++t) {
    float racc = 0.f;
    if (tid < 400) {
      const float* hp = &ha[q4*100];
      #pragma unroll
      for (int i = 0; i < 25; ++i) {
        float4 h4 = *(const float4*)&hp[i*4];
        racc = fmaf(rw[i*4], h4.x, racc);
        racc = fmaf(rw[i*4+1], h4.y, racc);
        racc = fmaf(rw[i*4+2], h4.z, racc);
        racc = fmaf(rw[i*4+3], h4.w, racc);
      }
      racc += __shfl_xor(racc, 1);
      racc += __shfl_xor(racc, 2);
      if (q4 == 0) rt[o] = tanhf(racc + rb[o]);
    }
    __syncthreads();
    if (tid < 400) {
      float qacc = 0.f;
      const float* rp = &rt[q4*25];
      #pragma unroll
      for (int i = 0; i < 25; ++i) qacc = fmaf(qw[i], rp[i], qacc);
      qacc += __shfl_xor(qacc, 1);
      qacc += __shfl_xor(qacc, 2);
      if (q4 == 0) qt[o] = tanhf(qacc + pq[t*100 + o]);
    }
    __syncthreads();
    if (tid < 400) ha[tid] = fmaf(Aa, ha[tid], Ba*qt[jq]);
    __syncthreads();
  }

  // head: out_last = tanh(Hf @ Ow^T + Ob), 2 threads per output
  if (tid < 256) {
    const int j2 = tid >> 1, hh = tid & 1;
    const float* osrc = &Ow[j2*400 + hh*200];
    const float* hp = &ha[hh*200];
    float oacc = 0.f;
    #pragma unroll
    for (int i = 0; i < 50; ++i) {
      float4 w4 = *(const float4*)&osrc[i*4];
      float4 h4 = *(const float4*)&hp[i*4];
      oacc = fmaf(w4.x, h4.x, oacc); oacc = fmaf(w4.y, h4.y, oacc);
      oacc = fmaf(w4.z, h4.z, oacc); oacc = fmaf(w4.w, h4.w, oacc);
    }
    oacc += __shfl_xor(oacc, 1);
    if (hh == 0) ol[j2] = tanhf(oacc + Ob[j2]);
  }
  __syncthreads();
  if (tid < 64) {
    float a = 0.f;
    #pragma unroll
    for (int i = 0; i < 32; ++i) {
      float4 w4 = *(const float4*)&f1w[tid*128 + i*4];
      float4 o4 = *(const float4*)&ol[i*4];
      a = fmaf(w4.x, o4.x, a); a = fmaf(w4.y, o4.y, a);
      a = fmaf(w4.z, o4.z, a); a = fmaf(w4.w, o4.w, a);
    }
    f1[tid] = fmaxf(a + f1b[tid], 0.f);
  }
  __syncthreads();
  if (tid == 0) {
    float a = 0.f;
    for (int i = 0; i < 64; ++i) a = fmaf(f2w[i], f1[i], a);
    out[b] = 1.f / (1.f + expf(-(a + f2b[0])));
  }
}

// ---------------------------------------------------------------------------
extern "C" void kernel_launch(void* const* d_in, const int* in_sizes, int n_in,
                              void* d_out, int out_size, void* d_ws, size_t ws_size,
                              hipStream_t stream) {
  (void)in_sizes; (void)n_in; (void)out_size; (void)ws_size;
  const float* x1   = (const float*)d_in[0];
  const float* x2   = (const float*)d_in[1];
  const float* c1w  = (const float*)d_in[2];
  // d_in[3] conv1_b: cancels in BN
  const float* bn1g = (const float*)d_in[4];
  const float* bn1b = (const float*)d_in[5];
  const float* c2w  = (const float*)d_in[6];
  // d_in[7] conv2_b: cancels in BN
  const float* bn2g = (const float*)d_in[8];
  const float* bn2b = (const float*)d_in[9];
  const float* Rw   = (const float*)d_in[10];
  const float* Rb   = (const float*)d_in[11];
  const float* Qw   = (const float*)d_in[12];
  const float* Qb   = (const float*)d_in[13];
  const float* Ow   = (const float*)d_in[14];
  const float* Ob   = (const float*)d_in[15];
  const float* f1w  = (const float*)d_in[16];
  const float* f1b  = (const float*)d_in[17];
  const float* f2w  = (const float*)d_in[18];
  const float* f2b  = (const float*)d_in[19];
  float* outp = (float*)d_out;

  // workspace layout (floats); peak ~99 MiB
  float* ws     = (float*)d_ws;
  float* pool1  = ws;                     // 16,777,216  (1024*64*16*16)
  float* feats  = pool1;                  // alias: 4,194,304 (pool1 dead by then)
  float* pmax   = ws + 16777216;          // 4,194,304
  float* pmin   = pmax + 4194304;         // 4,194,304
  float* part1  = pmin + 4194304;         // 131,072 (64*1024*2)
  float* part2  = part1 + 131072;         // 131,072
  float* bn1    = part2 + 131072;         // 128
  float* bn2    = bn1 + 128;              // 128
  float* pqpart = bn2 + 128;              // 409,600 (4*1024*100)
  float* preQ   = pqpart + 409600;        // 102,400

  conv1_kernel<true><<<dim3(1024,4), 256, 0, stream>>>(x1, x2, c1w, nullptr, part1);
  bn_finalize<<<64, 256, 0, stream>>>(part1, bn1g, bn1b, 1.f/1048576.f, bn1);
  conv1_kernel<false><<<dim3(1024,4), 256, 0, stream>>>(x1, x2, c1w, bn1, pool1);
  conv2_kernel<<<1024, 256, 0, stream>>>(pool1, c2w, part2, pmax, pmin);
  bn_finalize<<<64, 256, 0, stream>>>(part2, bn2g, bn2b, 1.f/262144.f, bn2);
  conv2_apply<<<16384, 256, 0, stream>>>(pmax, pmin, bn2, feats);
  preq_part<<<dim3(64,4), 256, 0, stream>>>(feats, Qw, pqpart);
  preq_reduce<<<400, 256, 0, stream>>>(pqpart, Qb, preQ);
  rnn_head<<<16, 512, 0, stream>>>(preQ, Rw, Rb, Qw, Ow, Ob, f1w, f1b, f2w, f2b, outp);
}

// Round 3
// 1227.074 us; speedup vs baseline: 1.2525x; 1.2525x over previous
//
#include <hip/hip_runtime.h>
#include <math.h>

// Problem constants
// x: (16,64,3,32,32) x2 concat -> (1024,6,32,32)
// conv1 6->64 k3 p1 -> BN -> ReLU -> pool2 -> (1024,64,16,16)
// conv2 64->64 k3 p1 -> BN -> ReLU -> pool2 -> (1024,64,8,8) = feats (1024,4096)
// RNN T=64 steps over feats rows n=b*64+t ; head -> sigmoid (16,1)

// ---------------------------------------------------------------------------
// conv1: template STATS pass (per-channel sum/sumsq partials) / APPLY pass.
// grid (1024, 8) -- 8 output channels per block, block 256.
// acc[8][4] = 32 VGPRs per thread (R1 post-mortem: acc[16][4] spilled, 256
// VGPR + 3.2 GB scratch traffic). Weights loaded to regs per co before FMAs.
// R2 post-mortem: weight staging MUST be a strided loop -- 432 elems > 256
// threads; the single-conditional version left wt[256..431] uninitialized.
// NOTE: conv bias cancels in BN (variance shift-invariant) -> never applied.
// ---------------------------------------------------------------------------
template<bool STATS>
__global__ __launch_bounds__(256)
void conv1_kernel(const float* __restrict__ x1, const float* __restrict__ x2,
                  const float* __restrict__ w1, const float* __restrict__ bn,
                  float* __restrict__ part, float* __restrict__ pool1)
{
  __shared__ float xin[6*34*34];   // padded 6x34x34
  __shared__ float wt[8*54];
  __shared__ float wred[4*8*2];
  const int n = blockIdx.x, ct = blockIdx.y, tid = threadIdx.x;

  for (int idx = tid; idx < 6*34*34; idx += 256) {
    int ci = idx / 1156, rem = idx - ci*1156;
    int r = rem / 34, c = rem - r*34;
    float v = 0.f;
    if (r >= 1 && r <= 32 && c >= 1 && c <= 32) {
      int p = (r-1)*32 + (c-1);
      v = (ci < 3) ? x1[n*3072 + ci*1024 + p] : x2[n*3072 + (ci-3)*1024 + p];
    }
    xin[idx] = v;
  }
  for (int idx = tid; idx < 8*54; idx += 256) wt[idx] = w1[ct*432 + idx];
  __syncthreads();

  const int ph = tid >> 4, pw = tid & 15;   // pooled coords (16x16)
  float acc[8][4];
  #pragma unroll
  for (int co = 0; co < 8; ++co) { acc[co][0]=0.f; acc[co][1]=0.f; acc[co][2]=0.f; acc[co][3]=0.f; }

  #pragma unroll
  for (int ci = 0; ci < 6; ++ci) {
    const float* base = &xin[ci*1156 + (2*ph)*34 + 2*pw];
    float r[4][4];
    #pragma unroll
    for (int i = 0; i < 4; ++i)
      #pragma unroll
      for (int j = 0; j < 4; ++j)
        r[i][j] = base[i*34 + j];
    #pragma unroll
    for (int co = 0; co < 8; ++co) {
      float w[9];
      #pragma unroll
      for (int k = 0; k < 9; ++k) w[k] = wt[co*54 + ci*9 + k];
      #pragma unroll
      for (int kh = 0; kh < 3; ++kh) {
        #pragma unroll
        for (int kw = 0; kw < 3; ++kw) {
          float wv = w[kh*3 + kw];
          acc[co][0] = fmaf(r[kh  ][kw  ], wv, acc[co][0]);
          acc[co][1] = fmaf(r[kh  ][kw+1], wv, acc[co][1]);
          acc[co][2] = fmaf(r[kh+1][kw  ], wv, acc[co][2]);
          acc[co][3] = fmaf(r[kh+1][kw+1], wv, acc[co][3]);
        }
      }
    }
  }

  if (STATS) {
    const int lane = tid & 63, wv = tid >> 6;
    #pragma unroll
    for (int co = 0; co < 8; ++co) {
      float s  = acc[co][0]+acc[co][1]+acc[co][2]+acc[co][3];
      float ss = acc[co][0]*acc[co][0]+acc[co][1]*acc[co][1]
               + acc[co][2]*acc[co][2]+acc[co][3]*acc[co][3];
      #pragma unroll
      for (int d = 32; d; d >>= 1) { s += __shfl_xor(s, d); ss += __shfl_xor(ss, d); }
      if (lane == 0) { wred[(wv*8+co)*2] = s; wred[(wv*8+co)*2+1] = ss; }
    }
    __syncthreads();
    if (tid < 8) {
      float s = 0.f, ss = 0.f;
      #pragma unroll
      for (int w = 0; w < 4; ++w) { s += wred[(w*8+tid)*2]; ss += wred[(w*8+tid)*2+1]; }
      int c = ct*8 + tid;
      part[c*2048 + n*2]     = s;   // layout [c][n][2] for coalesced finalize
      part[c*2048 + n*2 + 1] = ss;
    }
  } else {
    #pragma unroll
    for (int co = 0; co < 8; ++co) {
      int c = ct*8 + co;
      float sc = bn[c], sh = bn[64+c];
      float y0 = fmaxf(fmaf(acc[co][0], sc, sh), 0.f);
      float y1 = fmaxf(fmaf(acc[co][1], sc, sh), 0.f);
      float y2 = fmaxf(fmaf(acc[co][2], sc, sh), 0.f);
      float y3 = fmaxf(fmaf(acc[co][3], sc, sh), 0.f);
      pool1[((n*64 + c)*16 + ph)*16 + pw] = fmaxf(fmaxf(y0,y1), fmaxf(y2,y3));
    }
  }
}

// ---------------------------------------------------------------------------
// BN finalize: per-channel mean/var -> scale/shift.  grid 64, block 256.
// ---------------------------------------------------------------------------
__global__ __launch_bounds__(256)
void bn_finalize(const float* __restrict__ part, const float* __restrict__ g,
                 const float* __restrict__ beta, float inv_cnt, float* __restrict__ bn)
{
  __shared__ float red[8];
  const int c = blockIdx.x, tid = threadIdx.x;
  float s = 0.f, ss = 0.f;
  for (int n = tid; n < 1024; n += 256) {
    s  += part[c*2048 + n*2];
    ss += part[c*2048 + n*2 + 1];
  }
  #pragma unroll
  for (int d = 32; d; d >>= 1) { s += __shfl_xor(s, d); ss += __shfl_xor(ss, d); }
  if ((tid & 63) == 0) { red[(tid>>6)*2] = s; red[(tid>>6)*2+1] = ss; }
  __syncthreads();
  if (tid == 0) {
    float S  = red[0]+red[2]+red[4]+red[6];
    float SS = red[1]+red[3]+red[5]+red[7];
    float m  = S * inv_cnt;
    float var = SS * inv_cnt - m*m;
    float sc = g[c] * rsqrtf(var + 1e-5f);
    bn[c]    = sc;
    bn[64+c] = beta[c] - m*sc;
  }
}

// ---------------------------------------------------------------------------
// conv2 single pass: raw conv -> per-channel partial stats + pooled max AND min
// (pool commutes with channel affine; min kept so negative gamma stays correct)
// grid 1024, block 256 (cg=tid>>4 co-group of 4, pg=tid&15 pixel row).
// ---------------------------------------------------------------------------
__global__ __launch_bounds__(256)
void conv2_kernel(const float* __restrict__ pool1, const float* __restrict__ w2,
                  float* __restrict__ part, float* __restrict__ pmax, float* __restrict__ pmin)
{
  __shared__ float xin[8*18*18];   // 8-ci chunk, padded 18x18
  __shared__ float wt[64*8*9];
  const int n = blockIdx.x, tid = threadIdx.x;
  const int cg = tid >> 4, pg = tid & 15;
  float acc[4][16];
  #pragma unroll
  for (int a = 0; a < 4; ++a)
    #pragma unroll
    for (int b = 0; b < 16; ++b) acc[a][b] = 0.f;

  for (int ch = 0; ch < 8; ++ch) {
    const int ci0 = ch*8;
    for (int idx = tid; idx < 8*18*18; idx += 256) {
      int ci = idx / 324, rem = idx - ci*324;
      int r = rem / 18, c = rem - r*18;
      float v = 0.f;
      if (r >= 1 && r <= 16 && c >= 1 && c <= 16)
        v = pool1[(n*64 + ci0+ci)*256 + (r-1)*16 + (c-1)];
      xin[idx] = v;
    }
    for (int idx = tid; idx < 64*72; idx += 256) {
      int co = idx / 72, rem = idx - co*72;
      wt[idx] = w2[co*576 + ci0*9 + rem];
    }
    __syncthreads();
    #pragma unroll
    for (int ci = 0; ci < 8; ++ci) {
      #pragma unroll
      for (int kh = 0; kh < 3; ++kh) {
        const float* base = &xin[ci*324 + (pg+kh)*18];
        float r[18];
        #pragma unroll
        for (int j = 0; j < 18; ++j) r[j] = base[j];
        #pragma unroll
        for (int co = 0; co < 4; ++co) {
          const int wb = (cg*4+co)*72 + ci*9 + kh*3;
          float w0 = wt[wb], w1 = wt[wb+1], w2v = wt[wb+2];
          #pragma unroll
          for (int p = 0; p < 16; ++p)
            acc[co][p] = fmaf(r[p], w0, fmaf(r[p+1], w1, fmaf(r[p+2], w2v, acc[co][p])));
        }
      }
    }
    __syncthreads();
  }

  #pragma unroll
  for (int co = 0; co < 4; ++co) {
    const int c = cg*4 + co;
    float s = 0.f, ss = 0.f;
    #pragma unroll
    for (int p = 0; p < 16; ++p) { s += acc[co][p]; ss = fmaf(acc[co][p], acc[co][p], ss); }
    #pragma unroll
    for (int d = 1; d < 16; d <<= 1) { s += __shfl_xor(s, d); ss += __shfl_xor(ss, d); }
    if (pg == 0) { part[c*2048 + n*2] = s; part[c*2048 + n*2 + 1] = ss; }

    float hx[8], hn[8];
    #pragma unroll
    for (int w = 0; w < 8; ++w) {
      hx[w] = fmaxf(acc[co][2*w], acc[co][2*w+1]);
      hn[w] = fminf(acc[co][2*w], acc[co][2*w+1]);
    }
    #pragma unroll
    for (int w = 0; w < 8; ++w) {
      float ox = fmaxf(hx[w], __shfl_xor(hx[w], 1));   // rows pg, pg^1
      float on = fminf(hn[w], __shfl_xor(hn[w], 1));
      if (!(pg & 1)) {
        int off = ((n*64 + c) << 6) + (pg >> 1)*8 + w;   // feats layout n*4096+c*64+p
        pmax[off] = ox;
        pmin[off] = on;
      }
    }
  }
}

// feats = relu(affine(pooled raw)) -- elementwise.  grid 16384, block 256.
__global__ __launch_bounds__(256)
void conv2_apply(const float* __restrict__ pmax, const float* __restrict__ pmin,
                 const float* __restrict__ bn, float* __restrict__ feats)
{
  int idx = blockIdx.x*256 + threadIdx.x;   // 1024*4096 exact
  int c = (idx >> 6) & 63;
  float sc = bn[c], sh = bn[64+c];
  float v = (sc >= 0.f) ? pmax[idx] : pmin[idx];
  feats[idx] = fmaxf(fmaf(v, sc, sh), 0.f);
}

// ---------------------------------------------------------------------------
// preQ = feats @ Q_w[:, :4096]^T  (M=1024, K=4096, N=100), K split 4 ways.
// grid (64 rowblocks, 4 ksplit), block 256 (r=tid>>4 row, cg=tid&15).
// LDS padded stride 65 for bank-conflict-free reads; cols j = cg + 16*c.
// ---------------------------------------------------------------------------
__global__ __launch_bounds__(256)
void preq_part(const float* __restrict__ feats, const float* __restrict__ Qw,
               float* __restrict__ part)
{
  __shared__ float fL[16*65];
  __shared__ float qL[128*65];
  const int rb = blockIdx.x, ks = blockIdx.y, tid = threadIdx.x;
  const int r = tid >> 4, cg = tid & 15;
  const int n0 = rb*16, k0 = ks*1024;
  float acc[8];
  #pragma unroll
  for (int c = 0; c < 8; ++c) acc[c] = 0.f;

  for (int kk = 0; kk < 16; ++kk) {
    {
      int i = tid*4;
      int rr = i >> 6, cc = i & 63;
      float4 v = *(const float4*)&feats[(n0+rr)*4096 + k0 + kk*64 + cc];
      fL[rr*65+cc] = v.x; fL[rr*65+cc+1] = v.y; fL[rr*65+cc+2] = v.z; fL[rr*65+cc+3] = v.w;
    }
    #pragma unroll
    for (int t2 = 0; t2 < 8; ++t2) {
      int i = (tid + t2*256)*4;          // 0..8191
      int row = i >> 6, col = i & 63;
      float4 v = make_float4(0.f,0.f,0.f,0.f);
      if (row < 100) v = *(const float4*)&Qw[row*4196 + k0 + kk*64 + col];
      qL[row*65+col] = v.x; qL[row*65+col+1] = v.y; qL[row*65+col+2] = v.z; qL[row*65+col+3] = v.w;
    }
    __syncthreads();
    #pragma unroll 8
    for (int k = 0; k < 64; ++k) {
      float f = fL[r*65 + k];
      #pragma unroll
      for (int c = 0; c < 8; ++c)
        acc[c] = fmaf(f, qL[(cg + 16*c)*65 + k], acc[c]);
    }
    __syncthreads();
  }
  #pragma unroll
  for (int c = 0; c < 8; ++c) {
    int j = cg + 16*c;
    if (j < 100) part[(ks*1024 + n0 + r)*100 + j] = acc[c];
  }
}

__global__ __launch_bounds__(256)
void preq_reduce(const float* __restrict__ part, const float* __restrict__ Qb,
                 float* __restrict__ preQ)
{
  int idx = blockIdx.x*256 + threadIdx.x;  // 102400 exact
  if (idx < 1024*100) {
    int j = idx - (idx/100)*100;
    float s = part[idx] + part[102400 + idx] + part[2*102400 + idx] + part[3*102400 + idx];
    preQ[idx] = s + Qb[j];
  }
}

// ---------------------------------------------------------------------------
// RNN (64 sequential steps) + head. grid 16 (one block per batch b), block 512.
// Threads tid<400: o=tid>>2 output, q4=tid&3 k-quarter; R_w row quarter (100f)
// and Q_w recurrent quarter (25f) held in registers. Ha in LDS.
// ---------------------------------------------------------------------------
__global__ __launch_bounds__(512, 2)
void rnn_head(const float* __restrict__ preQ, const float* __restrict__ Rw,
              const float* __restrict__ Rb, const float* __restrict__ Qw,
              const float* __restrict__ Ow, const float* __restrict__ Ob,
              const float* __restrict__ f1w, const float* __restrict__ f1b,
              const float* __restrict__ f2w, const float* __restrict__ f2b,
              float* __restrict__ out)
{
  __shared__ __align__(16) float ha[400];
  __shared__ float rt[100];
  __shared__ float qt[100];
  __shared__ float pq[6400];
  __shared__ float rb[100];
  __shared__ __align__(16) float ol[128];
  __shared__ float f1[64];
  const int b = blockIdx.x, tid = threadIdx.x;

  for (int i = tid; i < 6400; i += 512) pq[i] = preQ[b*6400 + i];
  if (tid < 100) rb[tid] = Rb[tid];
  if (tid < 400) ha[tid] = 0.f;

  const int o = tid >> 2, q4 = tid & 3;
  float rw[100], qw[25];
  if (tid < 400) {
    const float* rsrc = &Rw[o*400 + q4*100];
    #pragma unroll
    for (int i = 0; i < 25; ++i) {
      float4 v = *(const float4*)&rsrc[i*4];
      rw[i*4] = v.x; rw[i*4+1] = v.y; rw[i*4+2] = v.z; rw[i*4+3] = v.w;
    }
    const float* qsrc = &Qw[o*4196 + 4096 + q4*25];
    #pragma unroll
    for (int i = 0; i < 25; ++i) qw[i] = qsrc[i];
  }
  const int ja = (tid < 400) ? (tid / 100) : 0;
  const int jq = tid - ja*100;
  const float Aa = (ja==0) ? 0.f : (ja==1) ? 0.25f : (ja==2) ? 0.5f : 0.95f;
  const float Ba = 1.f - Aa;
  __syncthreads();

  for (int t = 0; t < 64; ++t) {
    float racc = 0.f;
    if (tid < 400) {
      const float* hp = &ha[q4*100];
      #pragma unroll
      for (int i = 0; i < 25; ++i) {
        float4 h4 = *(const float4*)&hp[i*4];
        racc = fmaf(rw[i*4], h4.x, racc);
        racc = fmaf(rw[i*4+1], h4.y, racc);
        racc = fmaf(rw[i*4+2], h4.z, racc);
        racc = fmaf(rw[i*4+3], h4.w, racc);
      }
      racc += __shfl_xor(racc, 1);
      racc += __shfl_xor(racc, 2);
      if (q4 == 0) rt[o] = tanhf(racc + rb[o]);
    }
    __syncthreads();
    if (tid < 400) {
      float qacc = 0.f;
      const float* rp = &rt[q4*25];
      #pragma unroll
      for (int i = 0; i < 25; ++i) qacc = fmaf(qw[i], rp[i], qacc);
      qacc += __shfl_xor(qacc, 1);
      qacc += __shfl_xor(qacc, 2);
      if (q4 == 0) qt[o] = tanhf(qacc + pq[t*100 + o]);
    }
    __syncthreads();
    if (tid < 400) ha[tid] = fmaf(Aa, ha[tid], Ba*qt[jq]);
    __syncthreads();
  }

  // head: out_last = tanh(Hf @ Ow^T + Ob), 2 threads per output
  if (tid < 256) {
    const int j2 = tid >> 1, hh = tid & 1;
    const float* osrc = &Ow[j2*400 + hh*200];
    const float* hp = &ha[hh*200];
    float oacc = 0.f;
    #pragma unroll
    for (int i = 0; i < 50; ++i) {
      float4 w4 = *(const float4*)&osrc[i*4];
      float4 h4 = *(const float4*)&hp[i*4];
      oacc = fmaf(w4.x, h4.x, oacc); oacc = fmaf(w4.y, h4.y, oacc);
      oacc = fmaf(w4.z, h4.z, oacc); oacc = fmaf(w4.w, h4.w, oacc);
    }
    oacc += __shfl_xor(oacc, 1);
    if (hh == 0) ol[j2] = tanhf(oacc + Ob[j2]);
  }
  __syncthreads();
  if (tid < 64) {
    float a = 0.f;
    #pragma unroll
    for (int i = 0; i < 32; ++i) {
      float4 w4 = *(const float4*)&f1w[tid*128 + i*4];
      float4 o4 = *(const float4*)&ol[i*4];
      a = fmaf(w4.x, o4.x, a); a = fmaf(w4.y, o4.y, a);
      a = fmaf(w4.z, o4.z, a); a = fmaf(w4.w, o4.w, a);
    }
    f1[tid] = fmaxf(a + f1b[tid], 0.f);
  }
  __syncthreads();
  if (tid == 0) {
    float a = 0.f;
    for (int i = 0; i < 64; ++i) a = fmaf(f2w[i], f1[i], a);
    out[b] = 1.f / (1.f + expf(-(a + f2b[0])));
  }
}

// ---------------------------------------------------------------------------
extern "C" void kernel_launch(void* const* d_in, const int* in_sizes, int n_in,
                              void* d_out, int out_size, void* d_ws, size_t ws_size,
                              hipStream_t stream) {
  (void)in_sizes; (void)n_in; (void)out_size; (void)ws_size;
  const float* x1   = (const float*)d_in[0];
  const float* x2   = (const float*)d_in[1];
  const float* c1w  = (const float*)d_in[2];
  // d_in[3] conv1_b: cancels in BN
  const float* bn1g = (const float*)d_in[4];
  const float* bn1b = (const float*)d_in[5];
  const float* c2w  = (const float*)d_in[6];
  // d_in[7] conv2_b: cancels in BN
  const float* bn2g = (const float*)d_in[8];
  const float* bn2b = (const float*)d_in[9];
  const float* Rw   = (const float*)d_in[10];
  const float* Rb   = (const float*)d_in[11];
  const float* Qw   = (const float*)d_in[12];
  const float* Qb   = (const float*)d_in[13];
  const float* Ow   = (const float*)d_in[14];
  const float* Ob   = (const float*)d_in[15];
  const float* f1w  = (const float*)d_in[16];
  const float* f1b  = (const float*)d_in[17];
  const float* f2w  = (const float*)d_in[18];
  const float* f2b  = (const float*)d_in[19];
  float* outp = (float*)d_out;

  // workspace layout (floats); peak ~99 MiB
  float* ws     = (float*)d_ws;
  float* pool1  = ws;                     // 16,777,216  (1024*64*16*16)
  float* feats  = pool1;                  // alias: 4,194,304 (pool1 dead by then)
  float* pmax   = ws + 16777216;          // 4,194,304
  float* pmin   = pmax + 4194304;         // 4,194,304
  float* part1  = pmin + 4194304;         // 131,072 (64*1024*2)
  float* part2  = part1 + 131072;         // 131,072
  float* bn1    = part2 + 131072;         // 128
  float* bn2    = bn1 + 128;              // 128
  float* pqpart = bn2 + 128;              // 409,600 (4*1024*100)
  float* preQ   = pqpart + 409600;        // 102,400

  conv1_kernel<true><<<dim3(1024,8), 256, 0, stream>>>(x1, x2, c1w, nullptr, part1, nullptr);
  bn_finalize<<<64, 256, 0, stream>>>(part1, bn1g, bn1b, 1.f/1048576.f, bn1);
  conv1_kernel<false><<<dim3(1024,8), 256, 0, stream>>>(x1, x2, c1w, bn1, nullptr, pool1);
  conv2_kernel<<<1024, 256, 0, stream>>>(pool1, c2w, part2, pmax, pmin);
  bn_finalize<<<64, 256, 0, stream>>>(part2, bn2g, bn2b, 1.f/262144.f, bn2);
  conv2_apply<<<16384, 256, 0, stream>>>(pmax, pmin, bn2, feats);
  preq_part<<<dim3(64,4), 256, 0, stream>>>(feats, Qw, pqpart);
  preq_reduce<<<400, 256, 0, stream>>>(pqpart, Qb, preQ);
  rnn_head<<<16, 512, 0, stream>>>(preQ, Rw, Rb, Qw, Ow, Ob, f1w, f1b, f2w, f2b, outp);
}

// Round 4
// 759.034 us; speedup vs baseline: 2.0248x; 1.6166x over previous
//
#include <hip/hip_runtime.h>
#include <math.h>

// Problem constants
// x: (16,64,3,32,32) x2 concat -> (1024,6,32,32)
// conv1 6->64 k3 p1 -> BN -> ReLU -> pool2 -> (1024,64,16,16)
// conv2 64->64 k3 p1 -> BN -> ReLU -> pool2 -> (1024,64,8,8) = feats (1024,4096)
// RNN T=64 steps over feats rows n=b*64+t ; head -> sigmoid (16,1)

// ---------------------------------------------------------------------------
// conv1: template STATS pass (per-channel sum/sumsq partials) / APPLY pass.
// grid (1024, 8) -- 8 output channels per block, block 256.
// R3 post-mortem: full unroll of ci x co hoisted 432 LDS weight loads ->
// live-range explosion -> 256 VGPR + ~510 MB spill writes per dispatch.
// Fix: #pragma unroll 1 on ci loop (live set ~70 regs) + launch_bounds cap.
// NOTE: conv bias cancels in BN (variance shift-invariant) -> never applied.
// ---------------------------------------------------------------------------
template<bool STATS>
__global__ __launch_bounds__(256, 4)   // 4 waves/EU -> 128 VGPR cap
void conv1_kernel(const float* __restrict__ x1, const float* __restrict__ x2,
                  const float* __restrict__ w1, const float* __restrict__ bn,
                  float* __restrict__ part, float* __restrict__ pool1)
{
  __shared__ float xin[6*34*34];   // padded 6x34x34
  __shared__ float wt[8*54];
  __shared__ float wred[4*8*2];
  const int n = blockIdx.x, ct = blockIdx.y, tid = threadIdx.x;

  for (int idx = tid; idx < 6*34*34; idx += 256) {
    int ci = idx / 1156, rem = idx - ci*1156;
    int r = rem / 34, c = rem - r*34;
    float v = 0.f;
    if (r >= 1 && r <= 32 && c >= 1 && c <= 32) {
      int p = (r-1)*32 + (c-1);
      v = (ci < 3) ? x1[n*3072 + ci*1024 + p] : x2[n*3072 + (ci-3)*1024 + p];
    }
    xin[idx] = v;
  }
  for (int idx = tid; idx < 8*54; idx += 256) wt[idx] = w1[ct*432 + idx];
  __syncthreads();

  const int ph = tid >> 4, pw = tid & 15;   // pooled coords (16x16)
  float acc[8][4];
  #pragma unroll
  for (int co = 0; co < 8; ++co) { acc[co][0]=0.f; acc[co][1]=0.f; acc[co][2]=0.f; acc[co][3]=0.f; }

  #pragma unroll 1
  for (int ci = 0; ci < 6; ++ci) {
    const float* base = &xin[ci*1156 + (2*ph)*34 + 2*pw];
    float r[4][4];
    #pragma unroll
    for (int i = 0; i < 4; ++i)
      #pragma unroll
      for (int j = 0; j < 4; ++j)
        r[i][j] = base[i*34 + j];
    #pragma unroll
    for (int co = 0; co < 8; ++co) {
      float w[9];
      #pragma unroll
      for (int k = 0; k < 9; ++k) w[k] = wt[co*54 + ci*9 + k];
      #pragma unroll
      for (int kh = 0; kh < 3; ++kh) {
        #pragma unroll
        for (int kw = 0; kw < 3; ++kw) {
          float wv = w[kh*3 + kw];
          acc[co][0] = fmaf(r[kh  ][kw  ], wv, acc[co][0]);
          acc[co][1] = fmaf(r[kh  ][kw+1], wv, acc[co][1]);
          acc[co][2] = fmaf(r[kh+1][kw  ], wv, acc[co][2]);
          acc[co][3] = fmaf(r[kh+1][kw+1], wv, acc[co][3]);
        }
      }
    }
  }

  if (STATS) {
    const int lane = tid & 63, wv = tid >> 6;
    #pragma unroll
    for (int co = 0; co < 8; ++co) {
      float s  = acc[co][0]+acc[co][1]+acc[co][2]+acc[co][3];
      float ss = acc[co][0]*acc[co][0]+acc[co][1]*acc[co][1]
               + acc[co][2]*acc[co][2]+acc[co][3]*acc[co][3];
      #pragma unroll
      for (int d = 32; d; d >>= 1) { s += __shfl_xor(s, d); ss += __shfl_xor(ss, d); }
      if (lane == 0) { wred[(wv*8+co)*2] = s; wred[(wv*8+co)*2+1] = ss; }
    }
    __syncthreads();
    if (tid < 8) {
      float s = 0.f, ss = 0.f;
      #pragma unroll
      for (int w = 0; w < 4; ++w) { s += wred[(w*8+tid)*2]; ss += wred[(w*8+tid)*2+1]; }
      int c = ct*8 + tid;
      part[c*2048 + n*2]     = s;   // layout [c][n][2] for coalesced finalize
      part[c*2048 + n*2 + 1] = ss;
    }
  } else {
    #pragma unroll
    for (int co = 0; co < 8; ++co) {
      int c = ct*8 + co;
      float sc = bn[c], sh = bn[64+c];
      float y0 = fmaxf(fmaf(acc[co][0], sc, sh), 0.f);
      float y1 = fmaxf(fmaf(acc[co][1], sc, sh), 0.f);
      float y2 = fmaxf(fmaf(acc[co][2], sc, sh), 0.f);
      float y3 = fmaxf(fmaf(acc[co][3], sc, sh), 0.f);
      pool1[((n*64 + c)*16 + ph)*16 + pw] = fmaxf(fmaxf(y0,y1), fmaxf(y2,y3));
    }
  }
}

// ---------------------------------------------------------------------------
// BN finalize: per-channel mean/var -> scale/shift.  grid 64, block 256.
// ---------------------------------------------------------------------------
__global__ __launch_bounds__(256)
void bn_finalize(const float* __restrict__ part, const float* __restrict__ g,
                 const float* __restrict__ beta, float inv_cnt, float* __restrict__ bn)
{
  __shared__ float red[8];
  const int c = blockIdx.x, tid = threadIdx.x;
  float s = 0.f, ss = 0.f;
  for (int n = tid; n < 1024; n += 256) {
    s  += part[c*2048 + n*2];
    ss += part[c*2048 + n*2 + 1];
  }
  #pragma unroll
  for (int d = 32; d; d >>= 1) { s += __shfl_xor(s, d); ss += __shfl_xor(ss, d); }
  if ((tid & 63) == 0) { red[(tid>>6)*2] = s; red[(tid>>6)*2+1] = ss; }
  __syncthreads();
  if (tid == 0) {
    float S  = red[0]+red[2]+red[4]+red[6];
    float SS = red[1]+red[3]+red[5]+red[7];
    float m  = S * inv_cnt;
    float var = SS * inv_cnt - m*m;
    float sc = g[c] * rsqrtf(var + 1e-5f);
    bn[c]    = sc;
    bn[64+c] = beta[c] - m*sc;
  }
}

// ---------------------------------------------------------------------------
// conv2 single pass: raw conv -> per-channel partial stats + pooled max AND min
// (pool commutes with channel affine; min kept so negative gamma stays correct)
// grid 1024, block 256 (cg=tid>>4 co-group of 4, pg=tid&15 pixel row).
// R3 post-mortem medicine applied here too: ci/kh loops NOT unrolled so only
// one r[18] window is live (~95 regs incl. acc[4][16]); 128-VGPR cap.
// ---------------------------------------------------------------------------
__global__ __launch_bounds__(256, 4)
void conv2_kernel(const float* __restrict__ pool1, const float* __restrict__ w2,
                  float* __restrict__ part, float* __restrict__ pmax, float* __restrict__ pmin)
{
  __shared__ float xin[8*18*18];   // 8-ci chunk, padded 18x18
  __shared__ float wt[64*8*9];
  const int n = blockIdx.x, tid = threadIdx.x;
  const int cg = tid >> 4, pg = tid & 15;
  float acc[4][16];
  #pragma unroll
  for (int a = 0; a < 4; ++a)
    #pragma unroll
    for (int b = 0; b < 16; ++b) acc[a][b] = 0.f;

  for (int ch = 0; ch < 8; ++ch) {
    const int ci0 = ch*8;
    for (int idx = tid; idx < 8*18*18; idx += 256) {
      int ci = idx / 324, rem = idx - ci*324;
      int r = rem / 18, c = rem - r*18;
      float v = 0.f;
      if (r >= 1 && r <= 16 && c >= 1 && c <= 16)
        v = pool1[(n*64 + ci0+ci)*256 + (r-1)*16 + (c-1)];
      xin[idx] = v;
    }
    for (int idx = tid; idx < 64*72; idx += 256) {
      int co = idx / 72, rem = idx - co*72;
      wt[idx] = w2[co*576 + ci0*9 + rem];
    }
    __syncthreads();
    #pragma unroll 1
    for (int ci = 0; ci < 8; ++ci) {
      #pragma unroll 1
      for (int kh = 0; kh < 3; ++kh) {
        const float* base = &xin[ci*324 + (pg+kh)*18];
        float r[18];
        #pragma unroll
        for (int j = 0; j < 18; ++j) r[j] = base[j];
        #pragma unroll
        for (int co = 0; co < 4; ++co) {
          const int wb = (cg*4+co)*72 + ci*9 + kh*3;
          float w0 = wt[wb], w1 = wt[wb+1], w2v = wt[wb+2];
          #pragma unroll
          for (int p = 0; p < 16; ++p)
            acc[co][p] = fmaf(r[p], w0, fmaf(r[p+1], w1, fmaf(r[p+2], w2v, acc[co][p])));
        }
      }
    }
    __syncthreads();
  }

  #pragma unroll
  for (int co = 0; co < 4; ++co) {
    const int c = cg*4 + co;
    float s = 0.f, ss = 0.f;
    #pragma unroll
    for (int p = 0; p < 16; ++p) { s += acc[co][p]; ss = fmaf(acc[co][p], acc[co][p], ss); }
    #pragma unroll
    for (int d = 1; d < 16; d <<= 1) { s += __shfl_xor(s, d); ss += __shfl_xor(ss, d); }
    if (pg == 0) { part[c*2048 + n*2] = s; part[c*2048 + n*2 + 1] = ss; }

    float hx[8], hn[8];
    #pragma unroll
    for (int w = 0; w < 8; ++w) {
      hx[w] = fmaxf(acc[co][2*w], acc[co][2*w+1]);
      hn[w] = fminf(acc[co][2*w], acc[co][2*w+1]);
    }
    #pragma unroll
    for (int w = 0; w < 8; ++w) {
      float ox = fmaxf(hx[w], __shfl_xor(hx[w], 1));   // rows pg, pg^1
      float on = fminf(hn[w], __shfl_xor(hn[w], 1));
      if (!(pg & 1)) {
        int off = ((n*64 + c) << 6) + (pg >> 1)*8 + w;   // feats layout n*4096+c*64+p
        pmax[off] = ox;
        pmin[off] = on;
      }
    }
  }
}

// feats = relu(affine(pooled raw)) -- elementwise.  grid 16384, block 256.
__global__ __launch_bounds__(256)
void conv2_apply(const float* __restrict__ pmax, const float* __restrict__ pmin,
                 const float* __restrict__ bn, float* __restrict__ feats)
{
  int idx = blockIdx.x*256 + threadIdx.x;   // 1024*4096 exact
  int c = (idx >> 6) & 63;
  float sc = bn[c], sh = bn[64+c];
  float v = (sc >= 0.f) ? pmax[idx] : pmin[idx];
  feats[idx] = fmaxf(fmaf(v, sc, sh), 0.f);
}

// ---------------------------------------------------------------------------
// preQ = feats @ Q_w[:, :4096]^T  (M=1024, K=4096, N=100), K split 4 ways.
// grid (64 rowblocks, 4 ksplit), block 256 (r=tid>>4 row, cg=tid&15).
// LDS padded stride 65 for bank-conflict-free reads; cols j = cg + 16*c.
// ---------------------------------------------------------------------------
__global__ __launch_bounds__(256)
void preq_part(const float* __restrict__ feats, const float* __restrict__ Qw,
               float* __restrict__ part)
{
  __shared__ float fL[16*65];
  __shared__ float qL[128*65];
  const int rb = blockIdx.x, ks = blockIdx.y, tid = threadIdx.x;
  const int r = tid >> 4, cg = tid & 15;
  const int n0 = rb*16, k0 = ks*1024;
  float acc[8];
  #pragma unroll
  for (int c = 0; c < 8; ++c) acc[c] = 0.f;

  for (int kk = 0; kk < 16; ++kk) {
    {
      int i = tid*4;
      int rr = i >> 6, cc = i & 63;
      float4 v = *(const float4*)&feats[(n0+rr)*4096 + k0 + kk*64 + cc];
      fL[rr*65+cc] = v.x; fL[rr*65+cc+1] = v.y; fL[rr*65+cc+2] = v.z; fL[rr*65+cc+3] = v.w;
    }
    #pragma unroll
    for (int t2 = 0; t2 < 8; ++t2) {
      int i = (tid + t2*256)*4;          // 0..8191
      int row = i >> 6, col = i & 63;
      float4 v = make_float4(0.f,0.f,0.f,0.f);
      if (row < 100) v = *(const float4*)&Qw[row*4196 + k0 + kk*64 + col];
      qL[row*65+col] = v.x; qL[row*65+col+1] = v.y; qL[row*65+col+2] = v.z; qL[row*65+col+3] = v.w;
    }
    __syncthreads();
    #pragma unroll 8
    for (int k = 0; k < 64; ++k) {
      float f = fL[r*65 + k];
      #pragma unroll
      for (int c = 0; c < 8; ++c)
        acc[c] = fmaf(f, qL[(cg + 16*c)*65 + k], acc[c]);
    }
    __syncthreads();
  }
  #pragma unroll
  for (int c = 0; c < 8; ++c) {
    int j = cg + 16*c;
    if (j < 100) part[(ks*1024 + n0 + r)*100 + j] = acc[c];
  }
}

__global__ __launch_bounds__(256)
void preq_reduce(const float* __restrict__ part, const float* __restrict__ Qb,
                 float* __restrict__ preQ)
{
  int idx = blockIdx.x*256 + threadIdx.x;  // 102400 exact
  if (idx < 1024*100) {
    int j = idx - (idx/100)*100;
    float s = part[idx] + part[102400 + idx] + part[2*102400 + idx] + part[3*102400 + idx];
    preQ[idx] = s + Qb[j];
  }
}

// ---------------------------------------------------------------------------
// RNN (64 sequential steps) + head. grid 16 (one block per batch b), block 512.
// Threads tid<400: o=tid>>2 output, q4=tid&3 k-quarter; R_w row quarter (100f)
// and Q_w recurrent quarter (25f) held in registers. Ha in LDS.
// ---------------------------------------------------------------------------
__global__ __launch_bounds__(512, 2)
void rnn_head(const float* __restrict__ preQ, const float* __restrict__ Rw,
              const float* __restrict__ Rb, const float* __restrict__ Qw,
              const float* __restrict__ Ow, const float* __restrict__ Ob,
              const float* __restrict__ f1w, const float* __restrict__ f1b,
              const float* __restrict__ f2w, const float* __restrict__ f2b,
              float* __restrict__ out)
{
  __shared__ __align__(16) float ha[400];
  __shared__ float rt[100];
  __shared__ float qt[100];
  __shared__ float pq[6400];
  __shared__ float rb[100];
  __shared__ __align__(16) float ol[128];
  __shared__ float f1[64];
  const int b = blockIdx.x, tid = threadIdx.x;

  for (int i = tid; i < 6400; i += 512) pq[i] = preQ[b*6400 + i];
  if (tid < 100) rb[tid] = Rb[tid];
  if (tid < 400) ha[tid] = 0.f;

  const int o = tid >> 2, q4 = tid & 3;
  float rw[100], qw[25];
  if (tid < 400) {
    const float* rsrc = &Rw[o*400 + q4*100];
    #pragma unroll
    for (int i = 0; i < 25; ++i) {
      float4 v = *(const float4*)&rsrc[i*4];
      rw[i*4] = v.x; rw[i*4+1] = v.y; rw[i*4+2] = v.z; rw[i*4+3] = v.w;
    }
    const float* qsrc = &Qw[o*4196 + 4096 + q4*25];
    #pragma unroll
    for (int i = 0; i < 25; ++i) qw[i] = qsrc[i];
  }
  const int ja = (tid < 400) ? (tid / 100) : 0;
  const int jq = tid - ja*100;
  const float Aa = (ja==0) ? 0.f : (ja==1) ? 0.25f : (ja==2) ? 0.5f : 0.95f;
  const float Ba = 1.f - Aa;
  __syncthreads();

  for (int t = 0; t < 64; ++t) {
    float racc = 0.f;
    if (tid < 400) {
      const float* hp = &ha[q4*100];
      #pragma unroll
      for (int i = 0; i < 25; ++i) {
        float4 h4 = *(const float4*)&hp[i*4];
        racc = fmaf(rw[i*4], h4.x, racc);
        racc = fmaf(rw[i*4+1], h4.y, racc);
        racc = fmaf(rw[i*4+2], h4.z, racc);
        racc = fmaf(rw[i*4+3], h4.w, racc);
      }
      racc += __shfl_xor(racc, 1);
      racc += __shfl_xor(racc, 2);
      if (q4 == 0) rt[o] = tanhf(racc + rb[o]);
    }
    __syncthreads();
    if (tid < 400) {
      float qacc = 0.f;
      const float* rp = &rt[q4*25];
      #pragma unroll
      for (int i = 0; i < 25; ++i) qacc = fmaf(qw[i], rp[i], qacc);
      qacc += __shfl_xor(qacc, 1);
      qacc += __shfl_xor(qacc, 2);
      if (q4 == 0) qt[o] = tanhf(qacc + pq[t*100 + o]);
    }
    __syncthreads();
    if (tid < 400) ha[tid] = fmaf(Aa, ha[tid], Ba*qt[jq]);
    __syncthreads();
  }

  // head: out_last = tanh(Hf @ Ow^T + Ob), 2 threads per output
  if (tid < 256) {
    const int j2 = tid >> 1, hh = tid & 1;
    const float* osrc = &Ow[j2*400 + hh*200];
    const float* hp = &ha[hh*200];
    float oacc = 0.f;
    #pragma unroll
    for (int i = 0; i < 50; ++i) {
      float4 w4 = *(const float4*)&osrc[i*4];
      float4 h4 = *(const float4*)&hp[i*4];
      oacc = fmaf(w4.x, h4.x, oacc); oacc = fmaf(w4.y, h4.y, oacc);
      oacc = fmaf(w4.z, h4.z, oacc); oacc = fmaf(w4.w, h4.w, oacc);
    }
    oacc += __shfl_xor(oacc, 1);
    if (hh == 0) ol[j2] = tanhf(oacc + Ob[j2]);
  }
  __syncthreads();
  if (tid < 64) {
    float a = 0.f;
    #pragma unroll
    for (int i = 0; i < 32; ++i) {
      float4 w4 = *(const float4*)&f1w[tid*128 + i*4];
      float4 o4 = *(const float4*)&ol[i*4];
      a = fmaf(w4.x, o4.x, a); a = fmaf(w4.y, o4.y, a);
      a = fmaf(w4.z, o4.z, a); a = fmaf(w4.w, o4.w, a);
    }
    f1[tid] = fmaxf(a + f1b[tid], 0.f);
  }
  __syncthreads();
  if (tid == 0) {
    float a = 0.f;
    for (int i = 0; i < 64; ++i) a = fmaf(f2w[i], f1[i], a);
    out[b] = 1.f / (1.f + expf(-(a + f2b[0])));
  }
}

// ---------------------------------------------------------------------------
extern "C" void kernel_launch(void* const* d_in, const int* in_sizes, int n_in,
                              void* d_out, int out_size, void* d_ws, size_t ws_size,
                              hipStream_t stream) {
  (void)in_sizes; (void)n_in; (void)out_size; (void)ws_size;
  const float* x1   = (const float*)d_in[0];
  const float* x2   = (const float*)d_in[1];
  const float* c1w  = (const float*)d_in[2];
  // d_in[3] conv1_b: cancels in BN
  const float* bn1g = (const float*)d_in[4];
  const float* bn1b = (const float*)d_in[5];
  const float* c2w  = (const float*)d_in[6];
  // d_in[7] conv2_b: cancels in BN
  const float* bn2g = (const float*)d_in[8];
  const float* bn2b = (const float*)d_in[9];
  const float* Rw   = (const float*)d_in[10];
  const float* Rb   = (const float*)d_in[11];
  const float* Qw   = (const float*)d_in[12];
  const float* Qb   = (const float*)d_in[13];
  const float* Ow   = (const float*)d_in[14];
  const float* Ob   = (const float*)d_in[15];
  const float* f1w  = (const float*)d_in[16];
  const float* f1b  = (const float*)d_in[17];
  const float* f2w  = (const float*)d_in[18];
  const float* f2b  = (const float*)d_in[19];
  float* outp = (float*)d_out;

  // workspace layout (floats); peak ~99 MiB
  float* ws     = (float*)d_ws;
  float* pool1  = ws;                     // 16,777,216  (1024*64*16*16)
  float* feats  = pool1;                  // alias: 4,194,304 (pool1 dead by then)
  float* pmax   = ws + 16777216;          // 4,194,304
  float* pmin   = pmax + 4194304;         // 4,194,304
  float* part1  = pmin + 4194304;         // 131,072 (64*1024*2)
  float* part2  = part1 + 131072;         // 131,072
  float* bn1    = part2 + 131072;         // 128
  float* bn2    = bn1 + 128;              // 128
  float* pqpart = bn2 + 128;              // 409,600 (4*1024*100)
  float* preQ   = pqpart + 409600;        // 102,400

  conv1_kernel<true><<<dim3(1024,8), 256, 0, stream>>>(x1, x2, c1w, nullptr, part1, nullptr);
  bn_finalize<<<64, 256, 0, stream>>>(part1, bn1g, bn1b, 1.f/1048576.f, bn1);
  conv1_kernel<false><<<dim3(1024,8), 256, 0, stream>>>(x1, x2, c1w, bn1, nullptr, pool1);
  conv2_kernel<<<1024, 256, 0, stream>>>(pool1, c2w, part2, pmax, pmin);
  bn_finalize<<<64, 256, 0, stream>>>(part2, bn2g, bn2b, 1.f/262144.f, bn2);
  conv2_apply<<<16384, 256, 0, stream>>>(pmax, pmin, bn2, feats);
  preq_part<<<dim3(64,4), 256, 0, stream>>>(feats, Qw, pqpart);
  preq_reduce<<<400, 256, 0, stream>>>(pqpart, Qb, preQ);
  rnn_head<<<16, 512, 0, stream>>>(preQ, Rw, Rb, Qw, Ow, Ob, f1w, f1b, f2w, f2b, outp);
}

// Round 5
// 552.637 us; speedup vs baseline: 2.7811x; 1.3735x over previous
//
#include <hip/hip_runtime.h>
#include <math.h>

// Problem constants
// x: (16,64,3,32,32) x2 concat -> (1024,6,32,32)
// conv1 6->64 k3 p1 -> BN -> ReLU -> pool2 -> (1024,64,16,16)
// conv2 64->64 k3 p1 -> BN -> ReLU -> pool2 -> (1024,64,8,8) = feats (1024,4096)
// RNN T=64 steps over feats rows n=b*64+t ; head -> sigmoid (16,1)

typedef __attribute__((ext_vector_type(8))) short s8v;   // 8 bf16 (4 VGPRs)
typedef __attribute__((ext_vector_type(4))) float f32x4;

__device__ __forceinline__ unsigned short f2bf(float f) {
  union { float f; unsigned u; } x; x.f = f;
  return (unsigned short)((x.u + 0x7FFFu + ((x.u >> 16) & 1u)) >> 16);  // RNE
}

// ---------------------------------------------------------------------------
// conv1: template STATS pass (per-channel sum/sumsq partials) / APPLY pass.
// grid (1024, 8) -- 8 output channels per block, block 256.
// R3 post-mortem: keep ci loop unroll 1 (full unroll -> live-range explosion
// -> 256 VGPR + spills). APPLY epilogue now emits bf16 channel-last pooled
// output pool1cl[n][py][px][c] for the MFMA conv2.
// NOTE: conv bias cancels in BN (variance shift-invariant) -> never applied.
// ---------------------------------------------------------------------------
template<bool STATS>
__global__ __launch_bounds__(256, 4)   // 4 waves/EU -> 128 VGPR cap
void conv1_kernel(const float* __restrict__ x1, const float* __restrict__ x2,
                  const float* __restrict__ w1, const float* __restrict__ bn,
                  float* __restrict__ part, unsigned short* __restrict__ pool1cl)
{
  __shared__ float xin[6*34*34];   // padded 6x34x34
  __shared__ float wt[8*54];
  __shared__ float wred[4*8*2];
  const int n = blockIdx.x, ct = blockIdx.y, tid = threadIdx.x;

  for (int idx = tid; idx < 6*34*34; idx += 256) {
    int ci = idx / 1156, rem = idx - ci*1156;
    int r = rem / 34, c = rem - r*34;
    float v = 0.f;
    if (r >= 1 && r <= 32 && c >= 1 && c <= 32) {
      int p = (r-1)*32 + (c-1);
      v = (ci < 3) ? x1[n*3072 + ci*1024 + p] : x2[n*3072 + (ci-3)*1024 + p];
    }
    xin[idx] = v;
  }
  for (int idx = tid; idx < 8*54; idx += 256) wt[idx] = w1[ct*432 + idx];
  __syncthreads();

  const int ph = tid >> 4, pw = tid & 15;   // pooled coords (16x16)
  float acc[8][4];
  #pragma unroll
  for (int co = 0; co < 8; ++co) { acc[co][0]=0.f; acc[co][1]=0.f; acc[co][2]=0.f; acc[co][3]=0.f; }

  #pragma unroll 1
  for (int ci = 0; ci < 6; ++ci) {
    const float* base = &xin[ci*1156 + (2*ph)*34 + 2*pw];
    float r[4][4];
    #pragma unroll
    for (int i = 0; i < 4; ++i)
      #pragma unroll
      for (int j = 0; j < 4; ++j)
        r[i][j] = base[i*34 + j];
    #pragma unroll
    for (int co = 0; co < 8; ++co) {
      float w[9];
      #pragma unroll
      for (int k = 0; k < 9; ++k) w[k] = wt[co*54 + ci*9 + k];
      #pragma unroll
      for (int kh = 0; kh < 3; ++kh) {
        #pragma unroll
        for (int kw = 0; kw < 3; ++kw) {
          float wv = w[kh*3 + kw];
          acc[co][0] = fmaf(r[kh  ][kw  ], wv, acc[co][0]);
          acc[co][1] = fmaf(r[kh  ][kw+1], wv, acc[co][1]);
          acc[co][2] = fmaf(r[kh+1][kw  ], wv, acc[co][2]);
          acc[co][3] = fmaf(r[kh+1][kw+1], wv, acc[co][3]);
        }
      }
    }
  }

  if (STATS) {
    const int lane = tid & 63, wv = tid >> 6;
    #pragma unroll
    for (int co = 0; co < 8; ++co) {
      float s  = acc[co][0]+acc[co][1]+acc[co][2]+acc[co][3];
      float ss = acc[co][0]*acc[co][0]+acc[co][1]*acc[co][1]
               + acc[co][2]*acc[co][2]+acc[co][3]*acc[co][3];
      #pragma unroll
      for (int d = 32; d; d >>= 1) { s += __shfl_xor(s, d); ss += __shfl_xor(ss, d); }
      if (lane == 0) { wred[(wv*8+co)*2] = s; wred[(wv*8+co)*2+1] = ss; }
    }
    __syncthreads();
    if (tid < 8) {
      float s = 0.f, ss = 0.f;
      #pragma unroll
      for (int w = 0; w < 4; ++w) { s += wred[(w*8+tid)*2]; ss += wred[(w*8+tid)*2+1]; }
      int c = ct*8 + tid;
      part[c*2048 + n*2]     = s;   // layout [c][n][2] for coalesced finalize
      part[c*2048 + n*2 + 1] = ss;
    }
  } else {
    s8v ov;
    #pragma unroll
    for (int co = 0; co < 8; ++co) {
      int c = ct*8 + co;
      float sc = bn[c], sh = bn[64+c];
      float y0 = fmaxf(fmaf(acc[co][0], sc, sh), 0.f);
      float y1 = fmaxf(fmaf(acc[co][1], sc, sh), 0.f);
      float y2 = fmaxf(fmaf(acc[co][2], sc, sh), 0.f);
      float y3 = fmaxf(fmaf(acc[co][3], sc, sh), 0.f);
      ov[co] = (short)f2bf(fmaxf(fmaxf(y0,y1), fmaxf(y2,y3)));
    }
    // channel-last bf16: [n][py][px][c], 8 consecutive c = one 16B store
    *(s8v*)&pool1cl[(((n<<8) + (ph<<4) + pw)<<6) + (ct<<3)] = ov;
  }
}

// ---------------------------------------------------------------------------
// BN finalize: per-channel mean/var -> scale/shift.  grid 64, block 256.
// ---------------------------------------------------------------------------
__global__ __launch_bounds__(256)
void bn_finalize(const float* __restrict__ part, const float* __restrict__ g,
                 const float* __restrict__ beta, float inv_cnt, float* __restrict__ bn)
{
  __shared__ float red[8];
  const int c = blockIdx.x, tid = threadIdx.x;
  float s = 0.f, ss = 0.f;
  for (int n = tid; n < 1024; n += 256) {
    s  += part[c*2048 + n*2];
    ss += part[c*2048 + n*2 + 1];
  }
  #pragma unroll
  for (int d = 32; d; d >>= 1) { s += __shfl_xor(s, d); ss += __shfl_xor(ss, d); }
  if ((tid & 63) == 0) { red[(tid>>6)*2] = s; red[(tid>>6)*2+1] = ss; }
  __syncthreads();
  if (tid == 0) {
    float S  = red[0]+red[2]+red[4]+red[6];
    float SS = red[1]+red[3]+red[5]+red[7];
    float m  = S * inv_cnt;
    float var = SS * inv_cnt - m*m;
    float sc = g[c] * rsqrtf(var + 1e-5f);
    bn[c]    = sc;
    bn[64+c] = beta[c] - m*sc;
  }
}

// ---------------------------------------------------------------------------
// w2 pack: fp32 [co][ci][kh][kw] -> bf16 [khw][co][ci] with the ci-chunk
// XOR-swizzle ((ci>>3)^(co&7)) pre-applied so conv2's LDS copy is linear.
// ---------------------------------------------------------------------------
__global__ __launch_bounds__(256)
void w2_pack(const float* __restrict__ w2, unsigned short* __restrict__ wB)
{
  int i = blockIdx.x*256 + threadIdx.x;   // 9*64*64 = 36864
  if (i < 36864) {
    int khw = i >> 12, rem = i & 4095, co = rem >> 6, ci = rem & 63;
    int chunk = (ci >> 3) ^ (co & 7);
    wB[khw*4096 + co*64 + chunk*8 + (ci & 7)] = f2bf(w2[co*576 + ci*9 + khw]);
  }
}

// ---------------------------------------------------------------------------
// conv2 via MFMA implicit GEMM. grid 1024 (one image), block 256 (4 waves).
// M=256 pixels (Mtile=py row), N=64 co, K=9*64 ((kh,kw)-major, ci inner).
// LDS: xin [18*18 lines][64 ci] bf16 + wL [9][64 co][64 ci] bf16, both with
// chunk^=(line&7) XOR swizzle (16B granules) -> ds_read_b128 conflict-free.
// Fragments: A row=lane&15=px, k=8*(lane>>4)+j ; B col=lane&15=co, same k;
// C/D col=lane&15=co, row=(lane>>4)*4+reg=px  [guide §3, m89-verified].
// Epilogue: per-channel sum/sumsq partials + 2x2 pooled max/min of raw conv.
// ---------------------------------------------------------------------------
__global__ __launch_bounds__(256)
void conv2_mfma(const unsigned short* __restrict__ pool1cl,
                const unsigned short* __restrict__ wB,
                float* __restrict__ part, float* __restrict__ pmax,
                float* __restrict__ pmin)
{
  __shared__ unsigned short xin[324*64];   // 41472 B
  __shared__ unsigned short wL[9*64*64];   // 73728 B
  __shared__ float wred[4][4][16][2];      // 2 KB
  const int n = blockIdx.x, tid = threadIdx.x;
  const int w = tid >> 6, lane = tid & 63;
  const int q = lane >> 4, col = lane & 15;

  // ---- stage weights (linear copy; swizzle pre-applied by w2_pack) ----
  {
    const s8v* src = (const s8v*)wB;
    s8v* dst = (s8v*)wL;
    #pragma unroll
    for (int i = 0; i < 18; ++i) dst[tid + (i<<8)] = src[tid + (i<<8)];
  }
  // ---- stage input 18x18x64 bf16, halo zeros, swizzled 16B chunks ----
  {
    #pragma unroll
    for (int k = 0; k < 11; ++k) {
      int i = tid + (k<<8);
      if (i < 324*8) {
        int L = i >> 3, s = i & 7;
        int y = L / 18, x = L - y*18;
        s8v v = (s8v){0,0,0,0,0,0,0,0};
        if (y >= 1 && y <= 16 && x >= 1 && x <= 16)
          v = *(const s8v*)&pool1cl[(((n<<8) + ((y-1)<<4) + (x-1))<<6) + (s<<3)];
        *(s8v*)((char*)xin + L*128 + (((s ^ (L & 7)) << 4))) = v;
      }
    }
  }
  __syncthreads();

  f32x4 acc[4][4];   // [mtile][ntile]
  #pragma unroll
  for (int mt = 0; mt < 4; ++mt)
    #pragma unroll
    for (int t = 0; t < 4; ++t)
      acc[mt][t] = (f32x4){0.f,0.f,0.f,0.f};

  const int py0 = w << 2;   // wave's 4 image rows
  #pragma unroll 1
  for (int khw = 0; khw < 9; ++khw) {
    const int kh = khw / 3, kw = khw - 3*kh;
    const char* wslice = (const char*)wL + khw*8192;
    #pragma unroll
    for (int ks = 0; ks < 2; ++ks) {       // ci0 = 32*ks
      const int chunk = (ks << 2) + q;     // 16B-chunk of k within line
      s8v bfrag[4];
      #pragma unroll
      for (int t = 0; t < 4; ++t) {
        int co = (t << 4) + col;
        bfrag[t] = *(const s8v*)(wslice + co*128 + (((chunk ^ (co & 7)) << 4)));
      }
      #pragma unroll
      for (int mt = 0; mt < 4; ++mt) {
        int L = (py0 + mt + kh)*18 + (col + kw);
        s8v afrag = *(const s8v*)((const char*)xin + L*128 + (((chunk ^ (L & 7)) << 4)));
        #pragma unroll
        for (int t = 0; t < 4; ++t)
          acc[mt][t] = __builtin_amdgcn_mfma_f32_16x16x32_bf16(afrag, bfrag[t], acc[mt][t], 0, 0, 0);
      }
    }
  }

  // ---- stats: per-channel sum / sumsq over this block's 256 pixels ----
  #pragma unroll
  for (int t = 0; t < 4; ++t) {
    float s = 0.f, ss = 0.f;
    #pragma unroll
    for (int mt = 0; mt < 4; ++mt)
      #pragma unroll
      for (int r = 0; r < 4; ++r) {
        float v = acc[mt][t][r];
        s += v; ss = fmaf(v, v, ss);
      }
    s  += __shfl_xor(s, 16);  s  += __shfl_xor(s, 32);
    ss += __shfl_xor(ss, 16); ss += __shfl_xor(ss, 32);
    if (q == 0) { wred[w][t][col][0] = s; wred[w][t][col][1] = ss; }
  }
  __syncthreads();
  if (tid < 64) {
    float s = 0.f, ss = 0.f;
    #pragma unroll
    for (int wv = 0; wv < 4; ++wv) {
      s  += wred[wv][tid >> 4][tid & 15][0];
      ss += wred[wv][tid >> 4][tid & 15][1];
    }
    part[tid*2048 + n*2]     = s;
    part[tid*2048 + n*2 + 1] = ss;
  }

  // ---- 2x2 pooled max AND min of raw conv (affine applied later) ----
  #pragma unroll
  for (int t = 0; t < 4; ++t) {
    int co = (t << 4) + col;
    #pragma unroll
    for (int mp = 0; mp < 2; ++mp) {          // vertical pair (rows 2mp,2mp+1)
      f32x4 a0 = acc[2*mp][t], a1 = acc[2*mp+1][t];
      float mx0 = fmaxf(fmaxf(a0[0], a0[1]), fmaxf(a1[0], a1[1]));
      float mx1 = fmaxf(fmaxf(a0[2], a0[3]), fmaxf(a1[2], a1[3]));
      float mn0 = fminf(fminf(a0[0], a0[1]), fminf(a1[0], a1[1]));
      float mn1 = fminf(fminf(a0[2], a0[3]), fminf(a1[2], a1[3]));
      int pyp = (w << 1) + mp;                // pooled y
      int base = ((n*64 + co) << 6) + (pyp << 3) + (q << 1);  // feats c*64+p
      pmax[base] = mx0; pmax[base+1] = mx1;
      pmin[base] = mn0; pmin[base+1] = mn1;
    }
  }
}

// feats = relu(affine(pooled raw)) -- elementwise.  grid 16384, block 256.
__global__ __launch_bounds__(256)
void conv2_apply(const float* __restrict__ pmax, const float* __restrict__ pmin,
                 const float* __restrict__ bn, float* __restrict__ feats)
{
  int idx = blockIdx.x*256 + threadIdx.x;   // 1024*4096 exact
  int c = (idx >> 6) & 63;
  float sc = bn[c], sh = bn[64+c];
  float v = (sc >= 0.f) ? pmax[idx] : pmin[idx];
  feats[idx] = fmaxf(fmaf(v, sc, sh), 0.f);
}

// ---------------------------------------------------------------------------
// preQ = feats @ Q_w[:, :4096]^T  (M=1024, K=4096, N=100), K split 4 ways.
// ---------------------------------------------------------------------------
__global__ __launch_bounds__(256)
void preq_part(const float* __restrict__ feats, const float* __restrict__ Qw,
               float* __restrict__ part)
{
  __shared__ float fL[16*65];
  __shared__ float qL[128*65];
  const int rb = blockIdx.x, ks = blockIdx.y, tid = threadIdx.x;
  const int r = tid >> 4, cg = tid & 15;
  const int n0 = rb*16, k0 = ks*1024;
  float acc[8];
  #pragma unroll
  for (int c = 0; c < 8; ++c) acc[c] = 0.f;

  for (int kk = 0; kk < 16; ++kk) {
    {
      int i = tid*4;
      int rr = i >> 6, cc = i & 63;
      float4 v = *(const float4*)&feats[(n0+rr)*4096 + k0 + kk*64 + cc];
      fL[rr*65+cc] = v.x; fL[rr*65+cc+1] = v.y; fL[rr*65+cc+2] = v.z; fL[rr*65+cc+3] = v.w;
    }
    #pragma unroll
    for (int t2 = 0; t2 < 8; ++t2) {
      int i = (tid + t2*256)*4;          // 0..8191
      int row = i >> 6, col = i & 63;
      float4 v = make_float4(0.f,0.f,0.f,0.f);
      if (row < 100) v = *(const float4*)&Qw[row*4196 + k0 + kk*64 + col];
      qL[row*65+col] = v.x; qL[row*65+col+1] = v.y; qL[row*65+col+2] = v.z; qL[row*65+col+3] = v.w;
    }
    __syncthreads();
    #pragma unroll 8
    for (int k = 0; k < 64; ++k) {
      float f = fL[r*65 + k];
      #pragma unroll
      for (int c = 0; c < 8; ++c)
        acc[c] = fmaf(f, qL[(cg + 16*c)*65 + k], acc[c]);
    }
    __syncthreads();
  }
  #pragma unroll
  for (int c = 0; c < 8; ++c) {
    int j = cg + 16*c;
    if (j < 100) part[(ks*1024 + n0 + r)*100 + j] = acc[c];
  }
}

__global__ __launch_bounds__(256)
void preq_reduce(const float* __restrict__ part, const float* __restrict__ Qb,
                 float* __restrict__ preQ)
{
  int idx = blockIdx.x*256 + threadIdx.x;  // 102400 exact
  if (idx < 1024*100) {
    int j = idx - (idx/100)*100;
    float s = part[idx] + part[102400 + idx] + part[2*102400 + idx] + part[3*102400 + idx];
    preQ[idx] = s + Qb[j];
  }
}

// ---------------------------------------------------------------------------
// RNN (64 sequential steps) + head. grid 16 (one block per batch b), block 512.
// ---------------------------------------------------------------------------
__global__ __launch_bounds__(512, 2)
void rnn_head(const float* __restrict__ preQ, const float* __restrict__ Rw,
              const float* __restrict__ Rb, const float* __restrict__ Qw,
              const float* __restrict__ Ow, const float* __restrict__ Ob,
              const float* __restrict__ f1w, const float* __restrict__ f1b,
              const float* __restrict__ f2w, const float* __restrict__ f2b,
              float* __restrict__ out)
{
  __shared__ __align__(16) float ha[400];
  __shared__ float rt[100];
  __shared__ float qt[100];
  __shared__ float pq[6400];
  __shared__ float rb[100];
  __shared__ __align__(16) float ol[128];
  __shared__ float f1[64];
  const int b = blockIdx.x, tid = threadIdx.x;

  for (int i = tid; i < 6400; i += 512) pq[i] = preQ[b*6400 + i];
  if (tid < 100) rb[tid] = Rb[tid];
  if (tid < 400) ha[tid] = 0.f;

  const int o = tid >> 2, q4 = tid & 3;
  float rw[100], qw[25];
  if (tid < 400) {
    const float* rsrc = &Rw[o*400 + q4*100];
    #pragma unroll
    for (int i = 0; i < 25; ++i) {
      float4 v = *(const float4*)&rsrc[i*4];
      rw[i*4] = v.x; rw[i*4+1] = v.y; rw[i*4+2] = v.z; rw[i*4+3] = v.w;
    }
    const float* qsrc = &Qw[o*4196 + 4096 + q4*25];
    #pragma unroll
    for (int i = 0; i < 25; ++i) qw[i] = qsrc[i];
  }
  const int ja = (tid < 400) ? (tid / 100) : 0;
  const int jq = tid - ja*100;
  const float Aa = (ja==0) ? 0.f : (ja==1) ? 0.25f : (ja==2) ? 0.5f : 0.95f;
  const float Ba = 1.f - Aa;
  __syncthreads();

  for (int t = 0; t < 64; ++t) {
    float racc = 0.f;
    if (tid < 400) {
      const float* hp = &ha[q4*100];
      #pragma unroll
      for (int i = 0; i < 25; ++i) {
        float4 h4 = *(const float4*)&hp[i*4];
        racc = fmaf(rw[i*4], h4.x, racc);
        racc = fmaf(rw[i*4+1], h4.y, racc);
        racc = fmaf(rw[i*4+2], h4.z, racc);
        racc = fmaf(rw[i*4+3], h4.w, racc);
      }
      racc += __shfl_xor(racc, 1);
      racc += __shfl_xor(racc, 2);
      if (q4 == 0) rt[o] = tanhf(racc + rb[o]);
    }
    __syncthreads();
    if (tid < 400) {
      float qacc = 0.f;
      const float* rp = &rt[q4*25];
      #pragma unroll
      for (int i = 0; i < 25; ++i) qacc = fmaf(qw[i], rp[i], qacc);
      qacc += __shfl_xor(qacc, 1);
      qacc += __shfl_xor(qacc, 2);
      if (q4 == 0) qt[o] = tanhf(qacc + pq[t*100 + o]);
    }
    __syncthreads();
    if (tid < 400) ha[tid] = fmaf(Aa, ha[tid], Ba*qt[jq]);
    __syncthreads();
  }

  if (tid < 256) {
    const int j2 = tid >> 1, hh = tid & 1;
    const float* osrc = &Ow[j2*400 + hh*200];
    const float* hp = &ha[hh*200];
    float oacc = 0.f;
    #pragma unroll
    for (int i = 0; i < 50; ++i) {
      float4 w4 = *(const float4*)&osrc[i*4];
      float4 h4 = *(const float4*)&hp[i*4];
      oacc = fmaf(w4.x, h4.x, oacc); oacc = fmaf(w4.y, h4.y, oacc);
      oacc = fmaf(w4.z, h4.z, oacc); oacc = fmaf(w4.w, h4.w, oacc);
    }
    oacc += __shfl_xor(oacc, 1);
    if (hh == 0) ol[j2] = tanhf(oacc + Ob[j2]);
  }
  __syncthreads();
  if (tid < 64) {
    float a = 0.f;
    #pragma unroll
    for (int i = 0; i < 32; ++i) {
      float4 w4 = *(const float4*)&f1w[tid*128 + i*4];
      float4 o4 = *(const float4*)&ol[i*4];
      a = fmaf(w4.x, o4.x, a); a = fmaf(w4.y, o4.y, a);
      a = fmaf(w4.z, o4.z, a); a = fmaf(w4.w, o4.w, a);
    }
    f1[tid] = fmaxf(a + f1b[tid], 0.f);
  }
  __syncthreads();
  if (tid == 0) {
    float a = 0.f;
    for (int i = 0; i < 64; ++i) a = fmaf(f2w[i], f1[i], a);
    out[b] = 1.f / (1.f + expf(-(a + f2b[0])));
  }
}

// ---------------------------------------------------------------------------
extern "C" void kernel_launch(void* const* d_in, const int* in_sizes, int n_in,
                              void* d_out, int out_size, void* d_ws, size_t ws_size,
                              hipStream_t stream) {
  (void)in_sizes; (void)n_in; (void)out_size; (void)ws_size;
  const float* x1   = (const float*)d_in[0];
  const float* x2   = (const float*)d_in[1];
  const float* c1w  = (const float*)d_in[2];
  // d_in[3] conv1_b: cancels in BN
  const float* bn1g = (const float*)d_in[4];
  const float* bn1b = (const float*)d_in[5];
  const float* c2w  = (const float*)d_in[6];
  // d_in[7] conv2_b: cancels in BN
  const float* bn2g = (const float*)d_in[8];
  const float* bn2b = (const float*)d_in[9];
  const float* Rw   = (const float*)d_in[10];
  const float* Rb   = (const float*)d_in[11];
  const float* Qw   = (const float*)d_in[12];
  const float* Qb   = (const float*)d_in[13];
  const float* Ow   = (const float*)d_in[14];
  const float* Ob   = (const float*)d_in[15];
  const float* f1w  = (const float*)d_in[16];
  const float* f1b  = (const float*)d_in[17];
  const float* f2w  = (const float*)d_in[18];
  const float* f2b  = (const float*)d_in[19];
  float* outp = (float*)d_out;

  // workspace layout; peak ~86 MiB
  char* wsb = (char*)d_ws;
  unsigned short* pool1cl = (unsigned short*)wsb;          // 33,554,432 B
  float* pmax   = (float*)(wsb + 33554432);                // 16,777,216 B
  float* pmin   = pmax + 4194304;                          // 16,777,216 B
  float* feats  = pmin + 4194304;                          // 16,777,216 B
  float* part1  = feats + 4194304;                         // 524,288 B
  float* part2  = part1 + 131072;                          // 524,288 B
  float* bn1    = part2 + 131072;                          // 512 B
  float* bn2    = bn1 + 128;                               // 512 B
  float* pqpart = bn2 + 128;                               // 1,638,400 B
  float* preQ   = pqpart + 409600;                         // 409,600 B
  unsigned short* wB = (unsigned short*)(preQ + 102400);   // 73,728 B

  conv1_kernel<true><<<dim3(1024,8), 256, 0, stream>>>(x1, x2, c1w, nullptr, part1, nullptr);
  bn_finalize<<<64, 256, 0, stream>>>(part1, bn1g, bn1b, 1.f/1048576.f, bn1);
  conv1_kernel<false><<<dim3(1024,8), 256, 0, stream>>>(x1, x2, c1w, bn1, nullptr, pool1cl);
  w2_pack<<<144, 256, 0, stream>>>(c2w, wB);
  conv2_mfma<<<1024, 256, 0, stream>>>(pool1cl, wB, part2, pmax, pmin);
  bn_finalize<<<64, 256, 0, stream>>>(part2, bn2g, bn2b, 1.f/262144.f, bn2);
  conv2_apply<<<16384, 256, 0, stream>>>(pmax, pmin, bn2, feats);
  preq_part<<<dim3(64,4), 256, 0, stream>>>(feats, Qw, pqpart);
  preq_reduce<<<400, 256, 0, stream>>>(pqpart, Qb, preQ);
  rnn_head<<<16, 512, 0, stream>>>(preQ, Rw, Rb, Qw, Ow, Ob, f1w, f1b, f2w, f2b, outp);
}

// Round 6
// 297.464 us; speedup vs baseline: 5.1668x; 1.8578x over previous
//
#include <hip/hip_runtime.h>
#include <math.h>

// Problem constants
// x: (16,64,3,32,32) x2 concat -> (1024,6,32,32)
// conv1 6->64 k3 p1 -> BN -> ReLU -> pool2 -> (1024,64,16,16)
// conv2 64->64 k3 p1 -> BN -> ReLU -> pool2 -> (1024,64,8,8) = feats (1024,4096)
// RNN T=64 steps over feats rows n=b*64+t ; head -> sigmoid (16,1)

typedef __attribute__((ext_vector_type(8))) short s8v;   // 8 bf16 (4 VGPRs)
typedef __attribute__((ext_vector_type(4))) float f32x4;

__device__ __forceinline__ unsigned short f2bf(float f) {
  union { float f; unsigned u; } x; x.f = f;
  return (unsigned short)((x.u + 0x7FFFu + ((x.u >> 16) & 1u)) >> 16);  // RNE
}
__device__ __forceinline__ float bf2f(unsigned short u) {
  union { unsigned u; float f; } x; x.u = ((unsigned)u) << 16; return x.f;
}

// ---------------------------------------------------------------------------
// w1 pack: fp32 [co][ci=6][kh][kw] -> bf16 [kh][64co][32k], k = kw*6+ci,
// ZEROS at k in [18,32) -- these multiply the A-side overread garbage.
// ---------------------------------------------------------------------------
__global__ __launch_bounds__(256)
void w1_pack(const float* __restrict__ w1, unsigned short* __restrict__ wB1)
{
  int i = blockIdx.x*256 + threadIdx.x;   // 3*64*32 = 6144
  if (i < 6144) {
    int kh = i >> 11, rem = i & 2047, co = rem >> 5, k2 = rem & 31;
    unsigned short v = 0;
    if (k2 < 18) {
      int kw = k2 / 6, ci = k2 - 6*kw;
      v = f2bf(w1[co*54 + ci*9 + kh*3 + kw]);
    }
    wB1[i] = v;
  }
}

// ---------------------------------------------------------------------------
// conv1 via MFMA implicit GEMM, computed ONCE (R5: two fp32 passes were 63%
// of runtime at 97% VALUBusy). grid 1024 (one image), block 256 (4 waves).
// M=1024 px (16-px x-strips), N=64 co, K=3kh x 32 (kw*6+ci, zero-padded).
// Channel-last bf16 image in LDS: row y (34 rows) x col x (36) x ci(6) ->
// the 18-wide (kw,ci) window is CONTIGUOUS -> A-frag = 4 ds_read_b32.
// Overreads beyond k=18 hit real-but-finite neighbor data (LDS fully
// zeroed first; zero B weights annihilate it). B-frags: 12 KB global
// (L2-broadcast) held in 48 VGPRs all kernel.
// Epilogue: per-channel sum/sumsq partials + 2x2 pooled max/min (bf16,
// channel-last) -- affine+relu applied later (pool commutes per sign).
// C layout col=lane&15=co, row=4q+reg=px [verified via conv2, R5 passed].
// ---------------------------------------------------------------------------
__global__ __launch_bounds__(256, 4)
void conv1_mfma(const float* __restrict__ x1, const float* __restrict__ x2,
                const unsigned short* __restrict__ wB1,
                float* __restrict__ part,
                unsigned short* __restrict__ pmax1, unsigned short* __restrict__ pmin1)
{
  __shared__ unsigned xin[3688];          // 34 rows x 108 dwords + 16 pad
  __shared__ float wred[4][4][16][2];
  const int n = blockIdx.x, tid = threadIdx.x;
  const int w = tid >> 6, lane = tid & 63;
  const int q = lane >> 4, r = lane & 15;

  // B fragments, whole kernel in regs: bf[kh][t], co = 16t + r, k0 = 8q
  s8v bf[3][4];
  #pragma unroll
  for (int kh = 0; kh < 3; ++kh)
    #pragma unroll
    for (int t = 0; t < 4; ++t)
      bf[kh][t] = *(const s8v*)&wB1[kh*2048 + (((t<<4)+r)<<5) + (q<<3)];

  // zero ALL of xin (incl. pad tail) -- overread garbage must be finite
  #pragma unroll
  for (int k = 0; k < 15; ++k) {
    int i = tid + (k<<8);
    if (i < 3688) xin[i] = 0;
  }
  __syncthreads();
  // interior fill: dword (y+1)*108 + (x+1)*3 + cp packs bf16{ci=2cp,2cp+1}
  #pragma unroll
  for (int k = 0; k < 12; ++k) {
    int i = tid + (k<<8);     // 0..3071
    int cp = i >> 10, p = i & 1023;
    int y = p >> 5, x = p & 31;
    float lo, hi;
    if (cp == 0)      { lo = x1[n*3072 + p];        hi = x1[n*3072 + 1024 + p]; }
    else if (cp == 1) { lo = x1[n*3072 + 2048 + p]; hi = x2[n*3072 + p];        }
    else              { lo = x2[n*3072 + 1024 + p]; hi = x2[n*3072 + 2048 + p]; }
    xin[(y+1)*108 + (x+1)*3 + cp] = (unsigned)f2bf(lo) | ((unsigned)f2bf(hi) << 16);
  }
  __syncthreads();

  float st[4], sq[4];
  #pragma unroll
  for (int t = 0; t < 4; ++t) { st[t] = 0.f; sq[t] = 0.f; }
  float pmx[4][2], pmn[4][2];

  #pragma unroll 1
  for (int xb = 0; xb < 2; ++xb) {
    const int xbase = xb << 4;
    #pragma unroll 2
    for (int j = 0; j < 8; ++j) {           // y = 8w + j
      const int y = (w << 3) + j;
      f32x4 acc[4];
      #pragma unroll
      for (int t = 0; t < 4; ++t) acc[t] = (f32x4){0.f,0.f,0.f,0.f};
      #pragma unroll
      for (int kh = 0; kh < 3; ++kh) {      // k-step == kh slice
        int dw = (y + kh)*108 + 3*(xbase + r) + (q << 2);
        union { unsigned u[4]; s8v v; } af;
        af.u[0] = xin[dw];   af.u[1] = xin[dw+1];
        af.u[2] = xin[dw+2]; af.u[3] = xin[dw+3];
        #pragma unroll
        for (int t = 0; t < 4; ++t)
          acc[t] = __builtin_amdgcn_mfma_f32_16x16x32_bf16(af.v, bf[kh][t], acc[t], 0, 0, 0);
      }
      #pragma unroll
      for (int t = 0; t < 4; ++t) {
        st[t] += acc[t][0]+acc[t][1]+acc[t][2]+acc[t][3];
        sq[t] = fmaf(acc[t][0],acc[t][0], fmaf(acc[t][1],acc[t][1],
                fmaf(acc[t][2],acc[t][2], fmaf(acc[t][3],acc[t][3], sq[t]))));
      }
      if ((j & 1) == 0) {                   // even y: stash x-pair max/min
        #pragma unroll
        for (int t = 0; t < 4; ++t) {
          pmx[t][0] = fmaxf(acc[t][0], acc[t][1]); pmx[t][1] = fmaxf(acc[t][2], acc[t][3]);
          pmn[t][0] = fminf(acc[t][0], acc[t][1]); pmn[t][1] = fminf(acc[t][2], acc[t][3]);
        }
      } else {                              // odd y: combine + write pooled
        const int py = y >> 1;
        #pragma unroll
        for (int t = 0; t < 4; ++t) {
          int co = (t << 4) + r;
          #pragma unroll
          for (int pp = 0; pp < 2; ++pp) {
            float mx = fmaxf(pmx[t][pp], fmaxf(acc[t][2*pp], acc[t][2*pp+1]));
            float mn = fminf(pmn[t][pp], fminf(acc[t][2*pp], acc[t][2*pp+1]));
            int pxp = (xb << 3) + (q << 1) + pp;
            int o = (((n << 8) + (py << 4) + pxp) << 6) + co;
            pmax1[o] = f2bf(mx);
            pmin1[o] = f2bf(mn);
          }
        }
      }
    }
  }

  #pragma unroll
  for (int t = 0; t < 4; ++t) {
    float s = st[t], ss = sq[t];
    s  += __shfl_xor(s, 16);  s  += __shfl_xor(s, 32);
    ss += __shfl_xor(ss, 16); ss += __shfl_xor(ss, 32);
    if (q == 0) { wred[w][t][r][0] = s; wred[w][t][r][1] = ss; }
  }
  __syncthreads();
  if (tid < 64) {
    float s = 0.f, ss = 0.f;
    #pragma unroll
    for (int wv = 0; wv < 4; ++wv) {
      s  += wred[wv][tid >> 4][tid & 15][0];
      ss += wred[wv][tid >> 4][tid & 15][1];
    }
    part[tid*2048 + n*2]     = s;     // layout [c][n][2]
    part[tid*2048 + n*2 + 1] = ss;
  }
}

// ---------------------------------------------------------------------------
// BN finalize: per-channel mean/var -> scale/shift.  grid 64, block 256.
// ---------------------------------------------------------------------------
__global__ __launch_bounds__(256)
void bn_finalize(const float* __restrict__ part, const float* __restrict__ g,
                 const float* __restrict__ beta, float inv_cnt, float* __restrict__ bn)
{
  __shared__ float red[8];
  const int c = blockIdx.x, tid = threadIdx.x;
  float s = 0.f, ss = 0.f;
  for (int n = tid; n < 1024; n += 256) {
    s  += part[c*2048 + n*2];
    ss += part[c*2048 + n*2 + 1];
  }
  #pragma unroll
  for (int d = 32; d; d >>= 1) { s += __shfl_xor(s, d); ss += __shfl_xor(ss, d); }
  if ((tid & 63) == 0) { red[(tid>>6)*2] = s; red[(tid>>6)*2+1] = ss; }
  __syncthreads();
  if (tid == 0) {
    float S  = red[0]+red[2]+red[4]+red[6];
    float SS = red[1]+red[3]+red[5]+red[7];
    float m  = S * inv_cnt;
    float var = SS * inv_cnt - m*m;
    float sc = g[c] * rsqrtf(var + 1e-5f);
    bn[c]    = sc;
    bn[64+c] = beta[c] - m*sc;
  }
}

// ---------------------------------------------------------------------------
// w2 pack: fp32 [co][ci][kh][kw] -> bf16 [khw][co][ci] with the ci-chunk
// XOR-swizzle ((ci>>3)^(co&7)) pre-applied so conv2's LDS copy is linear.
// ---------------------------------------------------------------------------
__global__ __launch_bounds__(256)
void w2_pack(const float* __restrict__ w2, unsigned short* __restrict__ wB)
{
  int i = blockIdx.x*256 + threadIdx.x;   // 9*64*64 = 36864
  if (i < 36864) {
    int khw = i >> 12, rem = i & 4095, co = rem >> 6, ci = rem & 63;
    int chunk = (ci >> 3) ^ (co & 7);
    wB[khw*4096 + co*64 + chunk*8 + (ci & 7)] = f2bf(w2[co*576 + ci*9 + khw]);
  }
}

// ---------------------------------------------------------------------------
// conv2 via MFMA implicit GEMM. grid 1024 (one image), block 256 (4 waves).
// Staging now FUSES conv1's BN affine + ReLU (reads pmax1/pmin1 bf16 + bn1),
// killing the separate conv1-apply pass. Pooled outputs stored bf16.
// ---------------------------------------------------------------------------
__global__ __launch_bounds__(256)
void conv2_mfma(const unsigned short* __restrict__ pmax1,
                const unsigned short* __restrict__ pmin1,
                const float* __restrict__ bn1,
                const unsigned short* __restrict__ wB,
                float* __restrict__ part,
                unsigned short* __restrict__ pmax2, unsigned short* __restrict__ pmin2)
{
  __shared__ unsigned short xin[324*64];   // 41472 B
  __shared__ unsigned short wL[9*64*64];   // 73728 B
  __shared__ float wred[4][4][16][2];      // 2 KB
  __shared__ float bnL[128];
  const int n = blockIdx.x, tid = threadIdx.x;
  const int w = tid >> 6, lane = tid & 63;
  const int q = lane >> 4, col = lane & 15;

  if (tid < 128) bnL[tid] = bn1[tid];
  // ---- stage weights (linear copy; swizzle pre-applied by w2_pack) ----
  {
    const s8v* src = (const s8v*)wB;
    s8v* dst = (s8v*)wL;
    #pragma unroll
    for (int i = 0; i < 18; ++i) dst[tid + (i<<8)] = src[tid + (i<<8)];
  }
  __syncthreads();   // bnL ready
  // ---- stage input 18x18x64 bf16 = relu(affine(pooled conv1)), halo zeros,
  //      swizzled 16B chunks ----
  {
    #pragma unroll
    for (int k = 0; k < 11; ++k) {
      int i = tid + (k<<8);
      if (i < 324*8) {
        int L = i >> 3, s = i & 7;
        int y = L / 18, x = L - y*18;
        s8v v = (s8v){0,0,0,0,0,0,0,0};
        if (y >= 1 && y <= 16 && x >= 1 && x <= 16) {
          int idx = (((n<<8) + ((y-1)<<4) + (x-1))<<6) + (s<<3);
          s8v mx = *(const s8v*)&pmax1[idx];
          s8v mn = *(const s8v*)&pmin1[idx];
          #pragma unroll
          for (int e = 0; e < 8; ++e) {
            int ci = (s<<3) + e;
            float sc = bnL[ci], sh = bnL[64+ci];
            float vv = bf2f((unsigned short)(sc >= 0.f ? mx[e] : mn[e]));
            v[e] = (short)f2bf(fmaxf(fmaf(vv, sc, sh), 0.f));
          }
        }
        *(s8v*)((char*)xin + L*128 + (((s ^ (L & 7)) << 4))) = v;
      }
    }
  }
  __syncthreads();

  f32x4 acc[4][4];   // [mtile][ntile]
  #pragma unroll
  for (int mt = 0; mt < 4; ++mt)
    #pragma unroll
    for (int t = 0; t < 4; ++t)
      acc[mt][t] = (f32x4){0.f,0.f,0.f,0.f};

  const int py0 = w << 2;   // wave's 4 image rows
  #pragma unroll 1
  for (int khw = 0; khw < 9; ++khw) {
    const int kh = khw / 3, kw = khw - 3*kh;
    const char* wslice = (const char*)wL + khw*8192;
    #pragma unroll
    for (int ks = 0; ks < 2; ++ks) {       // ci0 = 32*ks
      const int chunk = (ks << 2) + q;     // 16B-chunk of k within line
      s8v bfrag[4];
      #pragma unroll
      for (int t = 0; t < 4; ++t) {
        int co = (t << 4) + col;
        bfrag[t] = *(const s8v*)(wslice + co*128 + (((chunk ^ (co & 7)) << 4)));
      }
      #pragma unroll
      for (int mt = 0; mt < 4; ++mt) {
        int L = (py0 + mt + kh)*18 + (col + kw);
        s8v afrag = *(const s8v*)((const char*)xin + L*128 + (((chunk ^ (L & 7)) << 4)));
        #pragma unroll
        for (int t = 0; t < 4; ++t)
          acc[mt][t] = __builtin_amdgcn_mfma_f32_16x16x32_bf16(afrag, bfrag[t], acc[mt][t], 0, 0, 0);
      }
    }
  }

  // ---- stats: per-channel sum / sumsq over this block's 256 pixels ----
  #pragma unroll
  for (int t = 0; t < 4; ++t) {
    float s = 0.f, ss = 0.f;
    #pragma unroll
    for (int mt = 0; mt < 4; ++mt)
      #pragma unroll
      for (int r = 0; r < 4; ++r) {
        float v = acc[mt][t][r];
        s += v; ss = fmaf(v, v, ss);
      }
    s  += __shfl_xor(s, 16);  s  += __shfl_xor(s, 32);
    ss += __shfl_xor(ss, 16); ss += __shfl_xor(ss, 32);
    if (q == 0) { wred[w][t][col][0] = s; wred[w][t][col][1] = ss; }
  }
  __syncthreads();
  if (tid < 64) {
    float s = 0.f, ss = 0.f;
    #pragma unroll
    for (int wv = 0; wv < 4; ++wv) {
      s  += wred[wv][tid >> 4][tid & 15][0];
      ss += wred[wv][tid >> 4][tid & 15][1];
    }
    part[tid*2048 + n*2]     = s;
    part[tid*2048 + n*2 + 1] = ss;
  }

  // ---- 2x2 pooled max AND min of raw conv (affine applied later), bf16 ----
  #pragma unroll
  for (int t = 0; t < 4; ++t) {
    int co = (t << 4) + col;
    #pragma unroll
    for (int mp = 0; mp < 2; ++mp) {          // vertical pair (rows 2mp,2mp+1)
      f32x4 a0 = acc[2*mp][t], a1 = acc[2*mp+1][t];
      float mx0 = fmaxf(fmaxf(a0[0], a0[1]), fmaxf(a1[0], a1[1]));
      float mx1 = fmaxf(fmaxf(a0[2], a0[3]), fmaxf(a1[2], a1[3]));
      float mn0 = fminf(fminf(a0[0], a0[1]), fminf(a1[0], a1[1]));
      float mn1 = fminf(fminf(a0[2], a0[3]), fminf(a1[2], a1[3]));
      int pyp = (w << 1) + mp;                // pooled y
      int base = ((n*64 + co) << 6) + (pyp << 3) + (q << 1);  // feats c*64+p
      pmax2[base] = f2bf(mx0); pmax2[base+1] = f2bf(mx1);
      pmin2[base] = f2bf(mn0); pmin2[base+1] = f2bf(mn1);
    }
  }
}

// feats = relu(affine(pooled raw)) -- elementwise.  grid 16384, block 256.
__global__ __launch_bounds__(256)
void conv2_apply(const unsigned short* __restrict__ pmax,
                 const unsigned short* __restrict__ pmin,
                 const float* __restrict__ bn, float* __restrict__ feats)
{
  int idx = blockIdx.x*256 + threadIdx.x;   // 1024*4096 exact
  int c = (idx >> 6) & 63;
  float sc = bn[c], sh = bn[64+c];
  float v = bf2f((sc >= 0.f) ? pmax[idx] : pmin[idx]);
  feats[idx] = fmaxf(fmaf(v, sc, sh), 0.f);
}

// ---------------------------------------------------------------------------
// preQ = feats @ Q_w[:, :4096]^T  (M=1024, K=4096, N=100), K split 4 ways.
// ---------------------------------------------------------------------------
__global__ __launch_bounds__(256)
void preq_part(const float* __restrict__ feats, const float* __restrict__ Qw,
               float* __restrict__ part)
{
  __shared__ float fL[16*65];
  __shared__ float qL[128*65];
  const int rb = blockIdx.x, ks = blockIdx.y, tid = threadIdx.x;
  const int r = tid >> 4, cg = tid & 15;
  const int n0 = rb*16, k0 = ks*1024;
  float acc[8];
  #pragma unroll
  for (int c = 0; c < 8; ++c) acc[c] = 0.f;

  for (int kk = 0; kk < 16; ++kk) {
    {
      int i = tid*4;
      int rr = i >> 6, cc = i & 63;
      float4 v = *(const float4*)&feats[(n0+rr)*4096 + k0 + kk*64 + cc];
      fL[rr*65+cc] = v.x; fL[rr*65+cc+1] = v.y; fL[rr*65+cc+2] = v.z; fL[rr*65+cc+3] = v.w;
    }
    #pragma unroll
    for (int t2 = 0; t2 < 8; ++t2) {
      int i = (tid + t2*256)*4;          // 0..8191
      int row = i >> 6, col = i & 63;
      float4 v = make_float4(0.f,0.f,0.f,0.f);
      if (row < 100) v = *(const float4*)&Qw[row*4196 + k0 + kk*64 + col];
      qL[row*65+col] = v.x; qL[row*65+col+1] = v.y; qL[row*65+col+2] = v.z; qL[row*65+col+3] = v.w;
    }
    __syncthreads();
    #pragma unroll 8
    for (int k = 0; k < 64; ++k) {
      float f = fL[r*65 + k];
      #pragma unroll
      for (int c = 0; c < 8; ++c)
        acc[c] = fmaf(f, qL[(cg + 16*c)*65 + k], acc[c]);
    }
    __syncthreads();
  }
  #pragma unroll
  for (int c = 0; c < 8; ++c) {
    int j = cg + 16*c;
    if (j < 100) part[(ks*1024 + n0 + r)*100 + j] = acc[c];
  }
}

__global__ __launch_bounds__(256)
void preq_reduce(const float* __restrict__ part, const float* __restrict__ Qb,
                 float* __restrict__ preQ)
{
  int idx = blockIdx.x*256 + threadIdx.x;  // 102400 exact
  if (idx < 1024*100) {
    int j = idx - (idx/100)*100;
    float s = part[idx] + part[102400 + idx] + part[2*102400 + idx] + part[3*102400 + idx];
    preQ[idx] = s + Qb[j];
  }
}

// ---------------------------------------------------------------------------
// RNN (64 sequential steps) + head. grid 16 (one block per batch b), block 512.
// ---------------------------------------------------------------------------
__global__ __launch_bounds__(512, 2)
void rnn_head(const float* __restrict__ preQ, const float* __restrict__ Rw,
              const float* __restrict__ Rb, const float* __restrict__ Qw,
              const float* __restrict__ Ow, const float* __restrict__ Ob,
              const float* __restrict__ f1w, const float* __restrict__ f1b,
              const float* __restrict__ f2w, const float* __restrict__ f2b,
              float* __restrict__ out)
{
  __shared__ __align__(16) float ha[400];
  __shared__ float rt[100];
  __shared__ float qt[100];
  __shared__ float pq[6400];
  __shared__ float rb[100];
  __shared__ __align__(16) float ol[128];
  __shared__ float f1[64];
  const int b = blockIdx.x, tid = threadIdx.x;

  for (int i = tid; i < 6400; i += 512) pq[i] = preQ[b*6400 + i];
  if (tid < 100) rb[tid] = Rb[tid];
  if (tid < 400) ha[tid] = 0.f;

  const int o = tid >> 2, q4 = tid & 3;
  float rw[100], qw[25];
  if (tid < 400) {
    const float* rsrc = &Rw[o*400 + q4*100];
    #pragma unroll
    for (int i = 0; i < 25; ++i) {
      float4 v = *(const float4*)&rsrc[i*4];
      rw[i*4] = v.x; rw[i*4+1] = v.y; rw[i*4+2] = v.z; rw[i*4+3] = v.w;
    }
    const float* qsrc = &Qw[o*4196 + 4096 + q4*25];
    #pragma unroll
    for (int i = 0; i < 25; ++i) qw[i] = qsrc[i];
  }
  const int ja = (tid < 400) ? (tid / 100) : 0;
  const int jq = tid - ja*100;
  const float Aa = (ja==0) ? 0.f : (ja==1) ? 0.25f : (ja==2) ? 0.5f : 0.95f;
  const float Ba = 1.f - Aa;
  __syncthreads();

  for (int t = 0; t < 64; ++t) {
    float racc = 0.f;
    if (tid < 400) {
      const float* hp = &ha[q4*100];
      #pragma unroll
      for (int i = 0; i < 25; ++i) {
        float4 h4 = *(const float4*)&hp[i*4];
        racc = fmaf(rw[i*4], h4.x, racc);
        racc = fmaf(rw[i*4+1], h4.y, racc);
        racc = fmaf(rw[i*4+2], h4.z, racc);
        racc = fmaf(rw[i*4+3], h4.w, racc);
      }
      racc += __shfl_xor(racc, 1);
      racc += __shfl_xor(racc, 2);
      if (q4 == 0) rt[o] = tanhf(racc + rb[o]);
    }
    __syncthreads();
    if (tid < 400) {
      float qacc = 0.f;
      const float* rp = &rt[q4*25];
      #pragma unroll
      for (int i = 0; i < 25; ++i) qacc = fmaf(qw[i], rp[i], qacc);
      qacc += __shfl_xor(qacc, 1);
      qacc += __shfl_xor(qacc, 2);
      if (q4 == 0) qt[o] = tanhf(qacc + pq[t*100 + o]);
    }
    __syncthreads();
    if (tid < 400) ha[tid] = fmaf(Aa, ha[tid], Ba*qt[jq]);
    __syncthreads();
  }

  if (tid < 256) {
    const int j2 = tid >> 1, hh = tid & 1;
    const float* osrc = &Ow[j2*400 + hh*200];
    const float* hp = &ha[hh*200];
    float oacc = 0.f;
    #pragma unroll
    for (int i = 0; i < 50; ++i) {
      float4 w4 = *(const float4*)&osrc[i*4];
      float4 h4 = *(const float4*)&hp[i*4];
      oacc = fmaf(w4.x, h4.x, oacc); oacc = fmaf(w4.y, h4.y, oacc);
      oacc = fmaf(w4.z, h4.z, oacc); oacc = fmaf(w4.w, h4.w, oacc);
    }
    oacc += __shfl_xor(oacc, 1);
    if (hh == 0) ol[j2] = tanhf(oacc + Ob[j2]);
  }
  __syncthreads();
  if (tid < 64) {
    float a = 0.f;
    #pragma unroll
    for (int i = 0; i < 32; ++i) {
      float4 w4 = *(const float4*)&f1w[tid*128 + i*4];
      float4 o4 = *(const float4*)&ol[i*4];
      a = fmaf(w4.x, o4.x, a); a = fmaf(w4.y, o4.y, a);
      a = fmaf(w4.z, o4.z, a); a = fmaf(w4.w, o4.w, a);
    }
    f1[tid] = fmaxf(a + f1b[tid], 0.f);
  }
  __syncthreads();
  if (tid == 0) {
    float a = 0.f;
    for (int i = 0; i < 64; ++i) a = fmaf(f2w[i], f1[i], a);
    out[b] = 1.f / (1.f + expf(-(a + f2b[0])));
  }
}

// ---------------------------------------------------------------------------
extern "C" void kernel_launch(void* const* d_in, const int* in_sizes, int n_in,
                              void* d_out, int out_size, void* d_ws, size_t ws_size,
                              hipStream_t stream) {
  (void)in_sizes; (void)n_in; (void)out_size; (void)ws_size;
  const float* x1   = (const float*)d_in[0];
  const float* x2   = (const float*)d_in[1];
  const float* c1w  = (const float*)d_in[2];
  // d_in[3] conv1_b: cancels in BN
  const float* bn1g = (const float*)d_in[4];
  const float* bn1b = (const float*)d_in[5];
  const float* c2w  = (const float*)d_in[6];
  // d_in[7] conv2_b: cancels in BN
  const float* bn2g = (const float*)d_in[8];
  const float* bn2b = (const float*)d_in[9];
  const float* Rw   = (const float*)d_in[10];
  const float* Rb   = (const float*)d_in[11];
  const float* Qw   = (const float*)d_in[12];
  const float* Qb   = (const float*)d_in[13];
  const float* Ow   = (const float*)d_in[14];
  const float* Ob   = (const float*)d_in[15];
  const float* f1w  = (const float*)d_in[16];
  const float* f1b  = (const float*)d_in[17];
  const float* f2w  = (const float*)d_in[18];
  const float* f2b  = (const float*)d_in[19];
  float* outp = (float*)d_out;

  // workspace layout (bytes); total ~87 MB
  char* wsb = (char*)d_ws;
  unsigned short* pmax1 = (unsigned short*)wsb;                 // 33,554,432 B
  unsigned short* pmin1 = (unsigned short*)(wsb + 33554432);    // 33,554,432 B
  unsigned short* pmax2 = (unsigned short*)(wsb + 67108864);    //  8,388,608 B
  unsigned short* pmin2 = (unsigned short*)(wsb + 75497472);    //  8,388,608 B
  float* feats  = (float*)wsb;            // alias pmax1 (dead after conv2_mfma)
  float* part1  = (float*)(wsb + 83886080);                     // 524,288 B
  float* part2  = part1 + 131072;                               // 524,288 B
  float* bn1    = part2 + 131072;                               // 512 B
  float* bn2    = bn1 + 128;                                    // 512 B
  float* pqpart = bn2 + 128;                                    // 1,638,400 B
  float* preQ   = pqpart + 409600;                              // 409,600 B
  unsigned short* wB1 = (unsigned short*)(preQ + 102400);       // 12,288 B
  unsigned short* wB2 = wB1 + 6144;                             // 73,728 B

  w1_pack<<<24, 256, 0, stream>>>(c1w, wB1);
  w2_pack<<<144, 256, 0, stream>>>(c2w, wB2);
  conv1_mfma<<<1024, 256, 0, stream>>>(x1, x2, wB1, part1, pmax1, pmin1);
  bn_finalize<<<64, 256, 0, stream>>>(part1, bn1g, bn1b, 1.f/1048576.f, bn1);
  conv2_mfma<<<1024, 256, 0, stream>>>(pmax1, pmin1, bn1, wB2, part2, pmax2, pmin2);
  bn_finalize<<<64, 256, 0, stream>>>(part2, bn2g, bn2b, 1.f/262144.f, bn2);
  conv2_apply<<<16384, 256, 0, stream>>>(pmax2, pmin2, bn2, feats);
  preq_part<<<dim3(64,4), 256, 0, stream>>>(feats, Qw, pqpart);
  preq_reduce<<<400, 256, 0, stream>>>(pqpart, Qb, preQ);
  rnn_head<<<16, 512, 0, stream>>>(preQ, Rw, Rb, Qw, Ow, Ob, f1w, f1b, f2w, f2b, outp);
}

// Round 7
// 203.941 us; speedup vs baseline: 7.5361x; 1.4586x over previous
//
#include <hip/hip_runtime.h>
#include <math.h>

// Problem constants
// x: (16,64,3,32,32) x2 concat -> (1024,6,32,32)
// conv1 6->64 k3 p1 -> BN -> ReLU -> pool2 -> (1024,64,16,16)
// conv2 64->64 k3 p1 -> BN -> ReLU -> pool2 -> (1024,64,8,8) = feats (1024,4096)
// RNN T=64 steps over feats rows n=b*64+t ; head -> sigmoid (16,1)

typedef __attribute__((ext_vector_type(8))) short s8v;   // 8 bf16 (4 VGPRs)
typedef __attribute__((ext_vector_type(4))) float f32x4;

__device__ __forceinline__ unsigned short f2bf(float f) {
  union { float f; unsigned u; } x; x.f = f;
  return (unsigned short)((x.u + 0x7FFFu + ((x.u >> 16) & 1u)) >> 16);  // RNE
}
__device__ __forceinline__ float bf2f(unsigned short u) {
  union { unsigned u; float f; } x; x.u = ((unsigned)u) << 16; return x.f;
}

// ---------------------------------------------------------------------------
// w1 pack: fp32 [co][ci=6][kh][kw] -> bf16 [kh][64co][32k], k = kw*6+ci,
// ZEROS at k in [18,32) -- these multiply the A-side overread garbage.
// ---------------------------------------------------------------------------
__global__ __launch_bounds__(256)
void w1_pack(const float* __restrict__ w1, unsigned short* __restrict__ wB1)
{
  int i = blockIdx.x*256 + threadIdx.x;   // 3*64*32 = 6144
  if (i < 6144) {
    int kh = i >> 11, rem = i & 2047, co = rem >> 5, k2 = rem & 31;
    unsigned short v = 0;
    if (k2 < 18) {
      int kw = k2 / 6, ci = k2 - 6*kw;
      v = f2bf(w1[co*54 + ci*9 + kh*3 + kw]);
    }
    wB1[i] = v;
  }
}

// ---------------------------------------------------------------------------
// conv1 via MFMA implicit GEMM, computed ONCE. grid 1024, block 256 (4 waves).
// See R5/R6 notes. Epilogue: per-channel sum/sumsq + 2x2 pooled max/min bf16.
// ---------------------------------------------------------------------------
__global__ __launch_bounds__(256, 4)
void conv1_mfma(const float* __restrict__ x1, const float* __restrict__ x2,
                const unsigned short* __restrict__ wB1,
                float* __restrict__ part,
                unsigned short* __restrict__ pmax1, unsigned short* __restrict__ pmin1)
{
  __shared__ unsigned xin[3688];          // 34 rows x 108 dwords + 16 pad
  __shared__ float wred[4][4][16][2];
  const int n = blockIdx.x, tid = threadIdx.x;
  const int w = tid >> 6, lane = tid & 63;
  const int q = lane >> 4, r = lane & 15;

  // B fragments, whole kernel in regs: bf[kh][t], co = 16t + r, k0 = 8q
  s8v bf[3][4];
  #pragma unroll
  for (int kh = 0; kh < 3; ++kh)
    #pragma unroll
    for (int t = 0; t < 4; ++t)
      bf[kh][t] = *(const s8v*)&wB1[kh*2048 + (((t<<4)+r)<<5) + (q<<3)];

  // zero ALL of xin (incl. pad tail) -- overread garbage must be finite
  #pragma unroll
  for (int k = 0; k < 15; ++k) {
    int i = tid + (k<<8);
    if (i < 3688) xin[i] = 0;
  }
  __syncthreads();
  // interior fill: dword (y+1)*108 + (x+1)*3 + cp packs bf16{ci=2cp,2cp+1}
  #pragma unroll
  for (int k = 0; k < 12; ++k) {
    int i = tid + (k<<8);     // 0..3071
    int cp = i >> 10, p = i & 1023;
    int y = p >> 5, x = p & 31;
    float lo, hi;
    if (cp == 0)      { lo = x1[n*3072 + p];        hi = x1[n*3072 + 1024 + p]; }
    else if (cp == 1) { lo = x1[n*3072 + 2048 + p]; hi = x2[n*3072 + p];        }
    else              { lo = x2[n*3072 + 1024 + p]; hi = x2[n*3072 + 2048 + p]; }
    xin[(y+1)*108 + (x+1)*3 + cp] = (unsigned)f2bf(lo) | ((unsigned)f2bf(hi) << 16);
  }
  __syncthreads();

  float st[4], sq[4];
  #pragma unroll
  for (int t = 0; t < 4; ++t) { st[t] = 0.f; sq[t] = 0.f; }
  float pmx[4][2], pmn[4][2];

  #pragma unroll 1
  for (int xb = 0; xb < 2; ++xb) {
    const int xbase = xb << 4;
    #pragma unroll 2
    for (int j = 0; j < 8; ++j) {           // y = 8w + j
      const int y = (w << 3) + j;
      f32x4 acc[4];
      #pragma unroll
      for (int t = 0; t < 4; ++t) acc[t] = (f32x4){0.f,0.f,0.f,0.f};
      #pragma unroll
      for (int kh = 0; kh < 3; ++kh) {      // k-step == kh slice
        int dw = (y + kh)*108 + 3*(xbase + r) + (q << 2);
        union { unsigned u[4]; s8v v; } af;
        af.u[0] = xin[dw];   af.u[1] = xin[dw+1];
        af.u[2] = xin[dw+2]; af.u[3] = xin[dw+3];
        #pragma unroll
        for (int t = 0; t < 4; ++t)
          acc[t] = __builtin_amdgcn_mfma_f32_16x16x32_bf16(af.v, bf[kh][t], acc[t], 0, 0, 0);
      }
      #pragma unroll
      for (int t = 0; t < 4; ++t) {
        st[t] += acc[t][0]+acc[t][1]+acc[t][2]+acc[t][3];
        sq[t] = fmaf(acc[t][0],acc[t][0], fmaf(acc[t][1],acc[t][1],
                fmaf(acc[t][2],acc[t][2], fmaf(acc[t][3],acc[t][3], sq[t]))));
      }
      if ((j & 1) == 0) {                   // even y: stash x-pair max/min
        #pragma unroll
        for (int t = 0; t < 4; ++t) {
          pmx[t][0] = fmaxf(acc[t][0], acc[t][1]); pmx[t][1] = fmaxf(acc[t][2], acc[t][3]);
          pmn[t][0] = fminf(acc[t][0], acc[t][1]); pmn[t][1] = fminf(acc[t][2], acc[t][3]);
        }
      } else {                              // odd y: combine + write pooled
        const int py = y >> 1;
        #pragma unroll
        for (int t = 0; t < 4; ++t) {
          int co = (t << 4) + r;
          #pragma unroll
          for (int pp = 0; pp < 2; ++pp) {
            float mx = fmaxf(pmx[t][pp], fmaxf(acc[t][2*pp], acc[t][2*pp+1]));
            float mn = fminf(pmn[t][pp], fminf(acc[t][2*pp], acc[t][2*pp+1]));
            int pxp = (xb << 3) + (q << 1) + pp;
            int o = (((n << 8) + (py << 4) + pxp) << 6) + co;
            pmax1[o] = f2bf(mx);
            pmin1[o] = f2bf(mn);
          }
        }
      }
    }
  }

  #pragma unroll
  for (int t = 0; t < 4; ++t) {
    float s = st[t], ss = sq[t];
    s  += __shfl_xor(s, 16);  s  += __shfl_xor(s, 32);
    ss += __shfl_xor(ss, 16); ss += __shfl_xor(ss, 32);
    if (q == 0) { wred[w][t][r][0] = s; wred[w][t][r][1] = ss; }
  }
  __syncthreads();
  if (tid < 64) {
    float s = 0.f, ss = 0.f;
    #pragma unroll
    for (int wv = 0; wv < 4; ++wv) {
      s  += wred[wv][tid >> 4][tid & 15][0];
      ss += wred[wv][tid >> 4][tid & 15][1];
    }
    part[tid*2048 + n*2]     = s;     // layout [c][n][2]
    part[tid*2048 + n*2 + 1] = ss;
  }
}

// ---------------------------------------------------------------------------
// BN finalize: per-channel mean/var -> scale/shift.  grid 64, block 256.
// ---------------------------------------------------------------------------
__global__ __launch_bounds__(256)
void bn_finalize(const float* __restrict__ part, const float* __restrict__ g,
                 const float* __restrict__ beta, float inv_cnt, float* __restrict__ bn)
{
  __shared__ float red[8];
  const int c = blockIdx.x, tid = threadIdx.x;
  float s = 0.f, ss = 0.f;
  for (int n = tid; n < 1024; n += 256) {
    s  += part[c*2048 + n*2];
    ss += part[c*2048 + n*2 + 1];
  }
  #pragma unroll
  for (int d = 32; d; d >>= 1) { s += __shfl_xor(s, d); ss += __shfl_xor(ss, d); }
  if ((tid & 63) == 0) { red[(tid>>6)*2] = s; red[(tid>>6)*2+1] = ss; }
  __syncthreads();
  if (tid == 0) {
    float S  = red[0]+red[2]+red[4]+red[6];
    float SS = red[1]+red[3]+red[5]+red[7];
    float m  = S * inv_cnt;
    float var = SS * inv_cnt - m*m;
    float sc = g[c] * rsqrtf(var + 1e-5f);
    bn[c]    = sc;
    bn[64+c] = beta[c] - m*sc;
  }
}

// ---------------------------------------------------------------------------
// w2 pack: fp32 [co][ci][kh][kw] -> bf16 [khw][co][ci] with the ci-chunk
// XOR-swizzle ((ci>>3)^(co&7)) pre-applied so conv2's LDS copy is linear.
// ---------------------------------------------------------------------------
__global__ __launch_bounds__(256)
void w2_pack(const float* __restrict__ w2, unsigned short* __restrict__ wB)
{
  int i = blockIdx.x*256 + threadIdx.x;   // 9*64*64 = 36864
  if (i < 36864) {
    int khw = i >> 12, rem = i & 4095, co = rem >> 6, ci = rem & 63;
    int chunk = (ci >> 3) ^ (co & 7);
    wB[khw*4096 + co*64 + chunk*8 + (ci & 7)] = f2bf(w2[co*576 + ci*9 + khw]);
  }
}

// ---------------------------------------------------------------------------
// Qw pack: fp32 [100][4196] (first 4096 cols) -> bf16 [112][4096],
// rows 100..111 zeroed (N padded to 7x16 MFMA tiles).
// ---------------------------------------------------------------------------
__global__ __launch_bounds__(256)
void qw_pack(const float* __restrict__ Qw, unsigned short* __restrict__ qB)
{
  int i = blockIdx.x*256 + threadIdx.x;   // 112*4096 = 458752
  if (i < 458752) {
    int j = i >> 12, k = i & 4095;
    qB[i] = (j < 100) ? f2bf(Qw[j*4196 + k]) : (unsigned short)0;
  }
}

// ---------------------------------------------------------------------------
// conv2 via MFMA implicit GEMM. grid 1024 (one image), block 256 (4 waves).
// Staging FUSES conv1's BN affine + ReLU. Pooled raw outputs stored bf16.
// ---------------------------------------------------------------------------
__global__ __launch_bounds__(256)
void conv2_mfma(const unsigned short* __restrict__ pmax1,
                const unsigned short* __restrict__ pmin1,
                const float* __restrict__ bn1,
                const unsigned short* __restrict__ wB,
                float* __restrict__ part,
                unsigned short* __restrict__ pmax2, unsigned short* __restrict__ pmin2)
{
  __shared__ unsigned short xin[324*64];   // 41472 B
  __shared__ unsigned short wL[9*64*64];   // 73728 B
  __shared__ float wred[4][4][16][2];      // 2 KB
  __shared__ float bnL[128];
  const int n = blockIdx.x, tid = threadIdx.x;
  const int w = tid >> 6, lane = tid & 63;
  const int q = lane >> 4, col = lane & 15;

  if (tid < 128) bnL[tid] = bn1[tid];
  // ---- stage weights (linear copy; swizzle pre-applied by w2_pack) ----
  {
    const s8v* src = (const s8v*)wB;
    s8v* dst = (s8v*)wL;
    #pragma unroll
    for (int i = 0; i < 18; ++i) dst[tid + (i<<8)] = src[tid + (i<<8)];
  }
  __syncthreads();   // bnL ready
  // ---- stage input 18x18x64 bf16 = relu(affine(pooled conv1)), halo zeros,
  //      swizzled 16B chunks ----
  {
    #pragma unroll
    for (int k = 0; k < 11; ++k) {
      int i = tid + (k<<8);
      if (i < 324*8) {
        int L = i >> 3, s = i & 7;
        int y = L / 18, x = L - y*18;
        s8v v = (s8v){0,0,0,0,0,0,0,0};
        if (y >= 1 && y <= 16 && x >= 1 && x <= 16) {
          int idx = (((n<<8) + ((y-1)<<4) + (x-1))<<6) + (s<<3);
          s8v mx = *(const s8v*)&pmax1[idx];
          s8v mn = *(const s8v*)&pmin1[idx];
          #pragma unroll
          for (int e = 0; e < 8; ++e) {
            int ci = (s<<3) + e;
            float sc = bnL[ci], sh = bnL[64+ci];
            float vv = bf2f((unsigned short)(sc >= 0.f ? mx[e] : mn[e]));
            v[e] = (short)f2bf(fmaxf(fmaf(vv, sc, sh), 0.f));
          }
        }
        *(s8v*)((char*)xin + L*128 + (((s ^ (L & 7)) << 4))) = v;
      }
    }
  }
  __syncthreads();

  f32x4 acc[4][4];   // [mtile][ntile]
  #pragma unroll
  for (int mt = 0; mt < 4; ++mt)
    #pragma unroll
    for (int t = 0; t < 4; ++t)
      acc[mt][t] = (f32x4){0.f,0.f,0.f,0.f};

  const int py0 = w << 2;   // wave's 4 image rows
  #pragma unroll 1
  for (int khw = 0; khw < 9; ++khw) {
    const int kh = khw / 3, kw = khw - 3*kh;
    const char* wslice = (const char*)wL + khw*8192;
    #pragma unroll
    for (int ks = 0; ks < 2; ++ks) {       // ci0 = 32*ks
      const int chunk = (ks << 2) + q;     // 16B-chunk of k within line
      s8v bfrag[4];
      #pragma unroll
      for (int t = 0; t < 4; ++t) {
        int co = (t << 4) + col;
        bfrag[t] = *(const s8v*)(wslice + co*128 + (((chunk ^ (co & 7)) << 4)));
      }
      #pragma unroll
      for (int mt = 0; mt < 4; ++mt) {
        int L = (py0 + mt + kh)*18 + (col + kw);
        s8v afrag = *(const s8v*)((const char*)xin + L*128 + (((chunk ^ (L & 7)) << 4)));
        #pragma unroll
        for (int t = 0; t < 4; ++t)
          acc[mt][t] = __builtin_amdgcn_mfma_f32_16x16x32_bf16(afrag, bfrag[t], acc[mt][t], 0, 0, 0);
      }
    }
  }

  // ---- stats: per-channel sum / sumsq over this block's 256 pixels ----
  #pragma unroll
  for (int t = 0; t < 4; ++t) {
    float s = 0.f, ss = 0.f;
    #pragma unroll
    for (int mt = 0; mt < 4; ++mt)
      #pragma unroll
      for (int r = 0; r < 4; ++r) {
        float v = acc[mt][t][r];
        s += v; ss = fmaf(v, v, ss);
      }
    s  += __shfl_xor(s, 16);  s  += __shfl_xor(s, 32);
    ss += __shfl_xor(ss, 16); ss += __shfl_xor(ss, 32);
    if (q == 0) { wred[w][t][col][0] = s; wred[w][t][col][1] = ss; }
  }
  __syncthreads();
  if (tid < 64) {
    float s = 0.f, ss = 0.f;
    #pragma unroll
    for (int wv = 0; wv < 4; ++wv) {
      s  += wred[wv][tid >> 4][tid & 15][0];
      ss += wred[wv][tid >> 4][tid & 15][1];
    }
    part[tid*2048 + n*2]     = s;
    part[tid*2048 + n*2 + 1] = ss;
  }

  // ---- 2x2 pooled max AND min of raw conv (affine applied later), bf16 ----
  #pragma unroll
  for (int t = 0; t < 4; ++t) {
    int co = (t << 4) + col;
    #pragma unroll
    for (int mp = 0; mp < 2; ++mp) {          // vertical pair (rows 2mp,2mp+1)
      f32x4 a0 = acc[2*mp][t], a1 = acc[2*mp+1][t];
      float mx0 = fmaxf(fmaxf(a0[0], a0[1]), fmaxf(a1[0], a1[1]));
      float mx1 = fmaxf(fmaxf(a0[2], a0[3]), fmaxf(a1[2], a1[3]));
      float mn0 = fminf(fminf(a0[0], a0[1]), fminf(a1[0], a1[1]));
      float mn1 = fminf(fminf(a0[2], a0[3]), fminf(a1[2], a1[3]));
      int pyp = (w << 1) + mp;                // pooled y
      int base = ((n*64 + co) << 6) + (pyp << 3) + (q << 1);  // feats c*64+p
      pmax2[base] = f2bf(mx0); pmax2[base+1] = f2bf(mx1);
      pmin2[base] = f2bf(mn0); pmin2[base+1] = f2bf(mn1);
    }
  }
}

// ---------------------------------------------------------------------------
// preQ partials via MFMA, FUSING conv2's BN affine + ReLU into the A-frag
// load (R6: fp32 preq_part was 118us at 20% VALUBusy / 11% occupancy;
// conv2_apply + fp32 feats deleted). No LDS: A from pmax2/pmin2 bf16 (L2-hot),
// B from qB bf16 [112][4096]. grid (16 mblocks x 16 ksplits), block 256.
// Each wave: 16 rows x 112 cols x 256 K -> 8 k-steps of 7 MFMAs.
// part layout [ks][1024][112] fp32.
// ---------------------------------------------------------------------------
__global__ __launch_bounds__(256)
void preq_mfma(const unsigned short* __restrict__ pmax2,
               const unsigned short* __restrict__ pmin2,
               const float* __restrict__ bn2,
               const unsigned short* __restrict__ qB,
               float* __restrict__ part)
{
  const int mb = blockIdx.x, ks = blockIdx.y, tid = threadIdx.x;
  const int w = tid >> 6, lane = tid & 63;
  const int q = lane >> 4, col = lane & 15;
  const int m = (mb << 6) + (w << 4) + col;    // A row this lane loads
  const int k00 = ks << 8;

  f32x4 acc[7];
  #pragma unroll
  for (int t = 0; t < 7; ++t) acc[t] = (f32x4){0.f,0.f,0.f,0.f};

  #pragma unroll 2
  for (int kk = 0; kk < 8; ++kk) {
    const int k = k00 + (kk << 5) + (q << 3);  // 8-aligned, one c per chunk
    const int c = k >> 6;
    const float sc = bn2[c], sh = bn2[64 + c];
    s8v mx = *(const s8v*)&pmax2[m*4096 + k];
    s8v mn = *(const s8v*)&pmin2[m*4096 + k];
    s8v a;
    #pragma unroll
    for (int e = 0; e < 8; ++e) {
      float vv = bf2f((unsigned short)(sc >= 0.f ? mx[e] : mn[e]));
      a[e] = (short)f2bf(fmaxf(fmaf(vv, sc, sh), 0.f));
    }
    #pragma unroll
    for (int t = 0; t < 7; ++t) {
      s8v b = *(const s8v*)&qB[(((t << 4) + col) << 12) + k];
      acc[t] = __builtin_amdgcn_mfma_f32_16x16x32_bf16(a, b, acc[t], 0, 0, 0);
    }
  }

  // C: col=lane&15 = j16, row=4q+r = m-row within the wave's 16-row tile
  float* dst = part + ks*114688 + ((mb << 6) + (w << 4) + (q << 2))*112;
  #pragma unroll
  for (int t = 0; t < 7; ++t)
    #pragma unroll
    for (int r = 0; r < 4; ++r)
      dst[r*112 + (t << 4) + col] = acc[t][r];
}

// preQ[n][100] = sum_ks part[ks][n][j] + Qb[j].  grid 400, block 256.
__global__ __launch_bounds__(256)
void preq_reduce(const float* __restrict__ part, const float* __restrict__ Qb,
                 float* __restrict__ preQ)
{
  int idx = blockIdx.x*256 + threadIdx.x;  // 102400 exact
  if (idx < 1024*100) {
    int n = idx / 100, j = idx - n*100;
    float s = Qb[j];
    #pragma unroll
    for (int ks = 0; ks < 16; ++ks) s += part[ks*114688 + n*112 + j];
    preQ[idx] = s;
  }
}

// ---------------------------------------------------------------------------
// RNN (64 sequential steps) + head. grid 16 (one block per batch b), block 512.
// ---------------------------------------------------------------------------
__global__ __launch_bounds__(512, 2)
void rnn_head(const float* __restrict__ preQ, const float* __restrict__ Rw,
              const float* __restrict__ Rb, const float* __restrict__ Qw,
              const float* __restrict__ Ow, const float* __restrict__ Ob,
              const float* __restrict__ f1w, const float* __restrict__ f1b,
              const float* __restrict__ f2w, const float* __restrict__ f2b,
              float* __restrict__ out)
{
  __shared__ __align__(16) float ha[400];
  __shared__ float rt[100];
  __shared__ float qt[100];
  __shared__ float pq[6400];
  __shared__ float rb[100];
  __shared__ __align__(16) float ol[128];
  __shared__ float f1[64];
  const int b = blockIdx.x, tid = threadIdx.x;

  for (int i = tid; i < 6400; i += 512) pq[i] = preQ[b*6400 + i];
  if (tid < 100) rb[tid] = Rb[tid];
  if (tid < 400) ha[tid] = 0.f;

  const int o = tid >> 2, q4 = tid & 3;
  float rw[100], qw[25];
  if (tid < 400) {
    const float* rsrc = &Rw[o*400 + q4*100];
    #pragma unroll
    for (int i = 0; i < 25; ++i) {
      float4 v = *(const float4*)&rsrc[i*4];
      rw[i*4] = v.x; rw[i*4+1] = v.y; rw[i*4+2] = v.z; rw[i*4+3] = v.w;
    }
    const float* qsrc = &Qw[o*4196 + 4096 + q4*25];
    #pragma unroll
    for (int i = 0; i < 25; ++i) qw[i] = qsrc[i];
  }
  const int ja = (tid < 400) ? (tid / 100) : 0;
  const int jq = tid - ja*100;
  const float Aa = (ja==0) ? 0.f : (ja==1) ? 0.25f : (ja==2) ? 0.5f : 0.95f;
  const float Ba = 1.f - Aa;
  __syncthreads();

  for (int t = 0; t < 64; ++t) {
    float racc = 0.f;
    if (tid < 400) {
      const float* hp = &ha[q4*100];
      #pragma unroll
      for (int i = 0; i < 25; ++i) {
        float4 h4 = *(const float4*)&hp[i*4];
        racc = fmaf(rw[i*4], h4.x, racc);
        racc = fmaf(rw[i*4+1], h4.y, racc);
        racc = fmaf(rw[i*4+2], h4.z, racc);
        racc = fmaf(rw[i*4+3], h4.w, racc);
      }
      racc += __shfl_xor(racc, 1);
      racc += __shfl_xor(racc, 2);
      if (q4 == 0) rt[o] = tanhf(racc + rb[o]);
    }
    __syncthreads();
    if (tid < 400) {
      float qacc = 0.f;
      const float* rp = &rt[q4*25];
      #pragma unroll
      for (int i = 0; i < 25; ++i) qacc = fmaf(qw[i], rp[i], qacc);
      qacc += __shfl_xor(qacc, 1);
      qacc += __shfl_xor(qacc, 2);
      if (q4 == 0) qt[o] = tanhf(qacc + pq[t*100 + o]);
    }
    __syncthreads();
    if (tid < 400) ha[tid] = fmaf(Aa, ha[tid], Ba*qt[jq]);
    __syncthreads();
  }

  if (tid < 256) {
    const int j2 = tid >> 1, hh = tid & 1;
    const float* osrc = &Ow[j2*400 + hh*200];
    const float* hp = &ha[hh*200];
    float oacc = 0.f;
    #pragma unroll
    for (int i = 0; i < 50; ++i) {
      float4 w4 = *(const float4*)&osrc[i*4];
      float4 h4 = *(const float4*)&hp[i*4];
      oacc = fmaf(w4.x, h4.x, oacc); oacc = fmaf(w4.y, h4.y, oacc);
      oacc = fmaf(w4.z, h4.z, oacc); oacc = fmaf(w4.w, h4.w, oacc);
    }
    oacc += __shfl_xor(oacc, 1);
    if (hh == 0) ol[j2] = tanhf(oacc + Ob[j2]);
  }
  __syncthreads();
  if (tid < 64) {
    float a = 0.f;
    #pragma unroll
    for (int i = 0; i < 32; ++i) {
      float4 w4 = *(const float4*)&f1w[tid*128 + i*4];
      float4 o4 = *(const float4*)&ol[i*4];
      a = fmaf(w4.x, o4.x, a); a = fmaf(w4.y, o4.y, a);
      a = fmaf(w4.z, o4.z, a); a = fmaf(w4.w, o4.w, a);
    }
    f1[tid] = fmaxf(a + f1b[tid], 0.f);
  }
  __syncthreads();
  if (tid == 0) {
    float a = 0.f;
    for (int i = 0; i < 64; ++i) a = fmaf(f2w[i], f1[i], a);
    out[b] = 1.f / (1.f + expf(-(a + f2b[0])));
  }
}

// ---------------------------------------------------------------------------
extern "C" void kernel_launch(void* const* d_in, const int* in_sizes, int n_in,
                              void* d_out, int out_size, void* d_ws, size_t ws_size,
                              hipStream_t stream) {
  (void)in_sizes; (void)n_in; (void)out_size; (void)ws_size;
  const float* x1   = (const float*)d_in[0];
  const float* x2   = (const float*)d_in[1];
  const float* c1w  = (const float*)d_in[2];
  // d_in[3] conv1_b: cancels in BN
  const float* bn1g = (const float*)d_in[4];
  const float* bn1b = (const float*)d_in[5];
  const float* c2w  = (const float*)d_in[6];
  // d_in[7] conv2_b: cancels in BN
  const float* bn2g = (const float*)d_in[8];
  const float* bn2b = (const float*)d_in[9];
  const float* Rw   = (const float*)d_in[10];
  const float* Rb   = (const float*)d_in[11];
  const float* Qw   = (const float*)d_in[12];
  const float* Qb   = (const float*)d_in[13];
  const float* Ow   = (const float*)d_in[14];
  const float* Ob   = (const float*)d_in[15];
  const float* f1w  = (const float*)d_in[16];
  const float* f1b  = (const float*)d_in[17];
  const float* f2w  = (const float*)d_in[18];
  const float* f2b  = (const float*)d_in[19];
  float* outp = (float*)d_out;

  // workspace layout (bytes); total ~90 MB
  char* wsb = (char*)d_ws;
  unsigned short* pmax1 = (unsigned short*)wsb;                 // 33,554,432 B
  unsigned short* pmin1 = (unsigned short*)(wsb + 33554432);    // 33,554,432 B
  unsigned short* pmax2 = (unsigned short*)(wsb + 67108864);    //  8,388,608 B
  unsigned short* pmin2 = (unsigned short*)(wsb + 75497472);    //  8,388,608 B
  float* part1  = (float*)(wsb + 83886080);                     // 524,288 B
  float* part2  = part1 + 131072;                               // 524,288 B
  float* bn1    = part2 + 131072;                               // 512 B
  float* bn2    = bn1 + 128;                                    // 512 B
  float* preQ   = bn2 + 128;                                    // 409,600 B
  unsigned short* wB1 = (unsigned short*)(preQ + 102400);       // 12,288 B
  unsigned short* wB2 = wB1 + 6144;                             // 73,728 B
  unsigned short* qB  = wB2 + 36864;                            // 917,504 B
  float* pqpart = (float*)(qB + 458752);                        // 7,340,032 B

  w1_pack<<<24, 256, 0, stream>>>(c1w, wB1);
  w2_pack<<<144, 256, 0, stream>>>(c2w, wB2);
  qw_pack<<<1792, 256, 0, stream>>>(Qw, qB);
  conv1_mfma<<<1024, 256, 0, stream>>>(x1, x2, wB1, part1, pmax1, pmin1);
  bn_finalize<<<64, 256, 0, stream>>>(part1, bn1g, bn1b, 1.f/1048576.f, bn1);
  conv2_mfma<<<1024, 256, 0, stream>>>(pmax1, pmin1, bn1, wB2, part2, pmax2, pmin2);
  bn_finalize<<<64, 256, 0, stream>>>(part2, bn2g, bn2b, 1.f/262144.f, bn2);
  preq_mfma<<<dim3(16,16), 256, 0, stream>>>(pmax2, pmin2, bn2, qB, pqpart);
  preq_reduce<<<400, 256, 0, stream>>>(pqpart, Qb, preQ);
  rnn_head<<<16, 512, 0, stream>>>(preQ, Rw, Rb, Qw, Ow, Ob, f1w, f1b, f2w, f2b, outp);
}